// Round 20
// baseline (225.036 us; speedup 1.0000x reference)
//
#include <hip/hip_runtime.h>
#include <hip/hip_bf16.h>
#include <math.h>

typedef unsigned short u16;
constexpr int Bc = 4, Hc = 48, Wc = 48, Cc = 256;
constexpr int NQc = 8, HWc = 2304, Nc = 2312, NHc = 8, Dc = 32, FFNc = 1024;
constexpr int MRc = Bc * Nc; // 9248
constexpr int KTLDc = 2368;  // padded kv length for transposed K (37*64)
constexpr float KSCALEc = 0.17677669529663687f; // (256/8)^-0.5
constexpr float LOG2Ec  = 1.4426950408889634f;

typedef __attribute__((ext_vector_type(8))) short s8v;
typedef __attribute__((ext_vector_type(4))) float f32x4;

__device__ __forceinline__ u16 f2bf(float f) {
    union { __hip_bfloat16 h; u16 u; } c;
    c.h = __float2bfloat16(f);
    return c.u;
}
__device__ __forceinline__ float bf2f(u16 u) {
    return __uint_as_float(((unsigned)u) << 16);
}
__device__ __forceinline__ unsigned cvtpk2(float lo, float hi) {
    unsigned r;
    asm("v_cvt_pk_bf16_f32 %0, %1, %2" : "=v"(r) : "v"(lo), "v"(hi));
    return r;
}
// raw v_exp_f32 (2^x), no OCML range fixup
__device__ __forceinline__ float fast_exp2(float x) {
    float r;
    asm("v_exp_f32 %0, %1" : "=v"(r) : "v"(x));
    return r;
}
// async global->LDS, 16B per lane; lds dest is wave-uniform base + lane*16
__device__ __forceinline__ void gload16(const void* g, void* l) {
    __builtin_amdgcn_global_load_lds((const __attribute__((address_space(1))) void*)g,
                                     (__attribute__((address_space(3))) void*)l, 16, 0, 0);
}

// ---------------- fused: pre (pos conv + LN1 + region softmax) / weight convert / kt pad-zero ----------------
__global__ __launch_bounds__(256) void fused_pre_kernel(
    const float* __restrict__ x, const float* __restrict__ queries, const int* __restrict__ epoch,
    const float* __restrict__ pos_w, const float* __restrict__ pos_b,
    const float* __restrict__ ln_g, const float* __restrict__ ln_b,
    const float* __restrict__ qw, const float* __restrict__ kw, const float* __restrict__ vw,
    const float* __restrict__ ow, const float* __restrict__ f1, const float* __restrict__ f2,
    float* __restrict__ xq, u16* __restrict__ ybf, u16* __restrict__ pbf,
    u16* __restrict__ wbf, u16* __restrict__ kt)
{
    int bi = blockIdx.x;
    if (bi >= 9248) {
        int bj = bi - 9248;
        if (bj < 768) {
            int i4 = bj * 256 + threadIdx.x;
            int idx = i4 * 4;
            const float* src; int off;
            if      (idx < 65536)  { src = qw; off = idx; }
            else if (idx < 131072) { src = kw; off = idx - 65536; }
            else if (idx < 196608) { src = vw; off = idx - 131072; }
            else if (idx < 262144) { src = ow; off = idx - 196608; }
            else if (idx < 524288) { src = f1; off = idx - 262144; }
            else                   { src = f2; off = idx - 524288; }
            float4 v = *(const float4*)(src + off);
            ushort4 o;
            o.x = f2bf(v.x); o.y = f2bf(v.y); o.z = f2bf(v.z); o.w = f2bf(v.w);
            *(ushort4*)(wbf + idx) = o;
        } else {
            int idx = (bj - 768) * 256 + threadIdx.x;  // 1024 rows * 56 pad cols
            if (idx < 1024 * 56) {
                int row = idx / 56, col = idx - row * 56;
                kt[(size_t)row * KTLDc + 2312 + col] = 0;
            }
        }
        return;
    }
    int blk = bi;                        // 0..9247
    int b = blk / Nc, n = blk - b * Nc;
    int c = threadIdx.x;
    bool sp = (n >= NQc);
    float val;
    if (sp) {
        int s = n - NQc;
        int hh = s / Wc, ww = s - hh * Wc;
        float acc = pos_b[c];
        float center = x[((b * Hc + hh) * Wc + ww) * Cc + c];
#pragma unroll
        for (int kh = 0; kh < 3; ++kh) {
            int yy = hh + kh - 1;
            if (yy < 0 || yy >= Hc) continue;
#pragma unroll
            for (int kw2 = 0; kw2 < 3; ++kw2) {
                int xx = ww + kw2 - 1;
                if (xx < 0 || xx >= Wc) continue;
                acc += x[((b * Hc + yy) * Wc + xx) * Cc + c] * pos_w[(kh * 3 + kw2) * Cc + c];
            }
        }
        val = center + acc;
    } else {
        val = queries[(b * NQc + n) * Cc + c];
    }
    xq[(size_t)blk * Cc + c] = val;

    float pq[8];
#pragma unroll
    for (int qi = 0; qi < 8; ++qi)
        pq[qi] = sp ? val * queries[(b * NQc + qi) * Cc + c] : 0.f;
    float r0 = val, r1 = val * val;
#pragma unroll
    for (int off = 32; off; off >>= 1) {
        r0 += __shfl_xor(r0, off);
        r1 += __shfl_xor(r1, off);
#pragma unroll
        for (int qi = 0; qi < 8; ++qi) pq[qi] += __shfl_xor(pq[qi], off);
    }
    __shared__ float red[4][10];
    __shared__ float fin[10];
    int wv = c >> 6, ln = c & 63;
    if (ln == 0) {
        red[wv][0] = r0; red[wv][1] = r1;
#pragma unroll
        for (int qi = 0; qi < 8; ++qi) red[wv][2 + qi] = pq[qi];
    }
    __syncthreads();
    if (c < 10) fin[c] = red[0][c] + red[1][c] + red[2][c] + red[3][c];
    __syncthreads();
    float mean = fin[0] * (1.0f / 256.0f);
    float var  = fin[1] * (1.0f / 256.0f) - mean * mean;
    float inv  = rsqrtf(var + 1e-6f);
    ybf[(size_t)blk * Cc + c] = f2bf((val - mean) * inv * ln_g[c] + ln_b[c]);

    if (sp && c < 8) {
        float it = 1.0f / (2.0f * powf(0.05f, (float)(*epoch) / 200.0f));
        float mx = -1e30f;
        float lg[8];
#pragma unroll
        for (int qi = 0; qi < 8; ++qi) { lg[qi] = fin[2 + qi] * it; mx = fmaxf(mx, lg[qi]); }
        float s = 0.f, mine = 0.f;
#pragma unroll
        for (int qi = 0; qi < 8; ++qi) {
            float ev = __expf(lg[qi] - mx);
            s += ev;
            if (qi == c) mine = ev;
        }
        pbf[((size_t)b * HWc + (n - NQc)) * 8 + c] = f2bf(mine / s);
    }
}

// ---------------- 64x128-tile GEMM (high block-count variant) ----------------
// OMODE: 0=f32 out, 1=bf16 out, 3=f32 out permuted to d_out layout (N==256)
template <int ACT, int RESID, int OMODE>
__global__ __launch_bounds__(256) void mfma_gemm64_kernel(
    const u16* __restrict__ A, const u16* __restrict__ W,
    const float* __restrict__ bias, const float* resid,
    float* outF, u16* outB, int M, int N, int K, float scale)
{
    __shared__ u16 As[64 * 64];
    __shared__ u16 Bs[128 * 64];
    int t = threadIdx.x;
    int w = t >> 6, l = t & 63, lg = l >> 4, lr = l & 15;
    int wm = w >> 1, wn = w & 1;
    int m0 = blockIdx.y * 64, n0 = blockIdx.x * 128;
    f32x4 acc[2][4] = {};
    int lrow = l >> 3, lchunk = (l & 7) * 8;
    for (int k0 = 0; k0 < K; k0 += 64) {
        __syncthreads();
#pragma unroll
        for (int c = 0; c < 2; ++c) {
            int ar = m0 + w * 16 + c * 8 + lrow;
            if (ar >= M) ar = M - 1;
            gload16(A + (size_t)ar * K + k0 + lchunk, As + (w * 16 + c * 8) * 64);
        }
#pragma unroll
        for (int c = 0; c < 4; ++c) {
            int br = n0 + w * 32 + c * 8 + lrow;
            gload16(W + (size_t)br * K + k0 + lchunk, Bs + (w * 32 + c * 8) * 64);
        }
        __syncthreads();
#pragma unroll
        for (int kk = 0; kk < 64; kk += 32) {
            s8v aF[2], bF[4];
#pragma unroll
            for (int i = 0; i < 2; ++i)
                aF[i] = *(s8v*)&As[(wm * 32 + i * 16 + lr) * 64 + kk + lg * 8];
#pragma unroll
            for (int j = 0; j < 4; ++j)
                bF[j] = *(s8v*)&Bs[(wn * 64 + j * 16 + lr) * 64 + kk + lg * 8];
#pragma unroll
            for (int i = 0; i < 2; ++i)
#pragma unroll
                for (int j = 0; j < 4; ++j)
                    acc[i][j] = __builtin_amdgcn_mfma_f32_16x16x32_bf16(aF[i], bF[j], acc[i][j], 0, 0, 0);
        }
    }
#pragma unroll
    for (int j = 0; j < 4; ++j) {
        int n = n0 + wn * 64 + j * 16 + lr;
        float bv = bias[n];
#pragma unroll
        for (int i = 0; i < 2; ++i) {
#pragma unroll
            for (int r = 0; r < 4; ++r) {
                int m = m0 + wm * 32 + i * 16 + lg * 4 + r;
                if (m >= M) continue;
                float v = (acc[i][j][r] + bv) * scale;
                if (ACT == 1) {
                    float e = fast_exp2(2.302118f * (v + 0.044715f * v * v * v));
                    v = v * e * __builtin_amdgcn_rcpf(e + 1.0f);
                }
                if (RESID) v += resid[(size_t)m * N + n];
                if (OMODE == 0) {
                    outF[(size_t)m * N + n] = v;
                } else if (OMODE == 3) {
                    unsigned bb2 = (unsigned)m / 2312u;
                    unsigned tok = (unsigned)m - bb2 * 2312u;
                    size_t ob = (tok >= 8) ? (((size_t)(bb2 * 2304 + tok - 8)) << 8)
                                           : ((size_t)2359296 + (((size_t)(bb2 * 8 + tok)) << 8));
                    outF[ob + n] = v;
                } else {
                    outB[(size_t)m * N + n] = f2bf(v);
                }
            }
        }
    }
}

// ---------------- fused lepe + out-proj + residual + LN2: 32x256 tile (full rows), 289 blocks ----------------
// A-tile = obf + dwconv5x5(vbf) staged once into padded LDS; out = A' @ w_o^T + out_b + xq; ybf = LN(out)
__global__ __launch_bounds__(256) void mfma_gemm_oln_kernel(
    const u16* __restrict__ A, const u16* __restrict__ V,
    const float* __restrict__ lw, const float* __restrict__ lbias,
    const u16* __restrict__ W, const float* __restrict__ bias,
    float* __restrict__ xq, const float* __restrict__ g, const float* __restrict__ bb,
    u16* __restrict__ ybf)
{
    const int K = Cc;
    constexpr int ALD = 264;        // padded row stride (u16): 528B -> 2-way banks
    __shared__ u16 As[32 * ALD];    // 16.5 KB (full K, staged once, lepe-fused)
    __shared__ u16 Bs[256 * 64];    // 32 KB
    __shared__ float R[32][4][2];
    __shared__ float MI[32][2];
    int t = threadIdx.x;
    int w = t >> 6, l = t & 63, lg = l >> 4, lr = l & 15;
    int m0 = blockIdx.x * 32;
    int lrow = l >> 3, lchunk = (l & 7) * 8;

    // ---- stage full A-tile with fused lepe conv (4 units of 8ch per thread) ----
    for (int u = t; u < 1024; u += 256) {
        int row = u >> 5;
        int cg  = (u & 31) * 8;
        int m = m0 + row;
        int b2 = m / 2312, n = m - b2 * 2312;
        union { s8v s; u16 us[8]; } ov, res;
        ov.s = *(const s8v*)&A[(size_t)m * Cc + cg];
        if (n >= NQc) {
            int s0 = n - NQc, hh = s0 / Wc, ww = s0 - hh * Wc;
            float accv[8];
#pragma unroll
            for (int i = 0; i < 8; ++i) accv[i] = lbias[cg + i];
#pragma unroll
            for (int kh = 0; kh < 5; ++kh) {
                int yy = hh + kh - 2;
                if (yy < 0 || yy >= Hc) continue;
#pragma unroll
                for (int kw = 0; kw < 5; ++kw) {
                    int xx = ww + kw - 2;
                    if (xx < 0 || xx >= Wc) continue;
                    union { s8v s; u16 us[8]; } uv;
                    uv.s = *(const s8v*)&V[((size_t)b2 * Nc + NQc + yy * Wc + xx) * Cc + cg];
                    const float4* wp = (const float4*)&lw[(kh * 5 + kw) * Cc + cg];
                    float4 w0 = wp[0], w1 = wp[1];
                    accv[0] += bf2f(uv.us[0]) * w0.x;
                    accv[1] += bf2f(uv.us[1]) * w0.y;
                    accv[2] += bf2f(uv.us[2]) * w0.z;
                    accv[3] += bf2f(uv.us[3]) * w0.w;
                    accv[4] += bf2f(uv.us[4]) * w1.x;
                    accv[5] += bf2f(uv.us[5]) * w1.y;
                    accv[6] += bf2f(uv.us[6]) * w1.z;
                    accv[7] += bf2f(uv.us[7]) * w1.w;
                }
            }
#pragma unroll
            for (int i = 0; i < 8; ++i) res.us[i] = f2bf(bf2f(ov.us[i]) + accv[i]);
        } else {
            res.s = ov.s;
        }
        *(s8v*)&As[row * ALD + cg] = res.s;
    }

    f32x4 acc[2][4] = {};
    for (int k0 = 0; k0 < K; k0 += 64) {
        __syncthreads();   // first iter also covers As writes
#pragma unroll
        for (int c = 0; c < 8; ++c)
            gload16(W + (size_t)(w * 64 + c * 8 + lrow) * K + k0 + lchunk, Bs + (w * 64 + c * 8) * 64);
        __syncthreads();
#pragma unroll
        for (int kk = 0; kk < 64; kk += 32) {
            s8v aF[2], bF[4];
#pragma unroll
            for (int i = 0; i < 2; ++i)
                aF[i] = *(s8v*)&As[(i * 16 + lr) * ALD + k0 + kk + lg * 8];
#pragma unroll
            for (int j = 0; j < 4; ++j)
                bF[j] = *(s8v*)&Bs[(w * 64 + j * 16 + lr) * 64 + kk + lg * 8];
#pragma unroll
            for (int i = 0; i < 2; ++i)
#pragma unroll
                for (int j = 0; j < 4; ++j)
                    acc[i][j] = __builtin_amdgcn_mfma_f32_16x16x32_bf16(aF[i], bF[j], acc[i][j], 0, 0, 0);
        }
    }
    float s[2][4], ss[2][4];
#pragma unroll
    for (int i = 0; i < 2; ++i)
#pragma unroll
        for (int r = 0; r < 4; ++r) { s[i][r] = 0.f; ss[i][r] = 0.f; }
#pragma unroll
    for (int j = 0; j < 4; ++j) {
        int n = w * 64 + j * 16 + lr;
        float bv = bias[n];
#pragma unroll
        for (int i = 0; i < 2; ++i) {
#pragma unroll
            for (int r = 0; r < 4; ++r) {
                int m = m0 + i * 16 + lg * 4 + r;
                float v = acc[i][j][r] + bv + xq[(size_t)m * Cc + n];
                acc[i][j][r] = v;
                xq[(size_t)m * Cc + n] = v;
                s[i][r] += v;
                ss[i][r] += v * v;
            }
        }
    }
#pragma unroll
    for (int i = 0; i < 2; ++i)
#pragma unroll
        for (int r = 0; r < 4; ++r) {
#pragma unroll
            for (int off = 1; off < 16; off <<= 1) {
                s[i][r]  += __shfl_xor(s[i][r], off);
                ss[i][r] += __shfl_xor(ss[i][r], off);
            }
        }
    __syncthreads();
    if (lr == 0) {
#pragma unroll
        for (int i = 0; i < 2; ++i)
#pragma unroll
            for (int r = 0; r < 4; ++r) {
                int row = i * 16 + lg * 4 + r;
                R[row][w][0] = s[i][r];
                R[row][w][1] = ss[i][r];
            }
    }
    __syncthreads();
    if (t < 32) {
        float tot  = R[t][0][0] + R[t][1][0] + R[t][2][0] + R[t][3][0];
        float tots = R[t][0][1] + R[t][1][1] + R[t][2][1] + R[t][3][1];
        float mean = tot * (1.0f / 256.0f);
        float var  = tots * (1.0f / 256.0f) - mean * mean;
        MI[t][0] = mean;
        MI[t][1] = rsqrtf(var + 1e-6f);
    }
    __syncthreads();
#pragma unroll
    for (int j = 0; j < 4; ++j) {
        int n = w * 64 + j * 16 + lr;
        float gv = g[n], bbv = bb[n];
#pragma unroll
        for (int i = 0; i < 2; ++i) {
#pragma unroll
            for (int r = 0; r < 4; ++r) {
                int row = i * 16 + lg * 4 + r;
                float mean = MI[row][0], inv = MI[row][1];
                int m = m0 + row;
                ybf[(size_t)m * Cc + n] = f2bf((acc[i][j][r] - mean) * inv * gv + bbv);
            }
        }
    }
}

// ---------------- fused QKV GEMM, 64x128 tile (870 blocks), N=768, K=256 ----------------
__global__ __launch_bounds__(256) void mfma_gemm_qkv64_kernel(
    const u16* __restrict__ A, const u16* __restrict__ W,
    const float* __restrict__ q_b, const float* __restrict__ k_b, const float* __restrict__ v_b,
    u16* __restrict__ outq, u16* __restrict__ outk, u16* __restrict__ outkt, u16* __restrict__ outv)
{
    const int M = MRc, K = Cc;
    __shared__ u16 As[64 * 64];
    __shared__ u16 Bs[128 * 64];
    int t = threadIdx.x;
    int w = t >> 6, l = t & 63, lg = l >> 4, lr = l & 15;
    int wm = w >> 1, wn = w & 1;
    int m0 = blockIdx.y * 64, n0 = blockIdx.x * 128;
    int range = n0 >> 8;  // n0 in {0,128,256,384,512,640} -> 0,0,1,1,2,2
    f32x4 acc[2][4] = {};
    int lrow = l >> 3, lchunk = (l & 7) * 8;
    for (int k0 = 0; k0 < K; k0 += 64) {
        __syncthreads();
#pragma unroll
        for (int c = 0; c < 2; ++c) {
            int ar = m0 + w * 16 + c * 8 + lrow;
            if (ar >= M) ar = M - 1;
            gload16(A + (size_t)ar * K + k0 + lchunk, As + (w * 16 + c * 8) * 64);
        }
#pragma unroll
        for (int c = 0; c < 4; ++c) {
            int br = n0 + w * 32 + c * 8 + lrow;
            gload16(W + (size_t)br * K + k0 + lchunk, Bs + (w * 32 + c * 8) * 64);
        }
        __syncthreads();
#pragma unroll
        for (int kk = 0; kk < 64; kk += 32) {
            s8v aF[2], bF[4];
#pragma unroll
            for (int i = 0; i < 2; ++i)
                aF[i] = *(s8v*)&As[(wm * 32 + i * 16 + lr) * 64 + kk + lg * 8];
#pragma unroll
            for (int j = 0; j < 4; ++j)
                bF[j] = *(s8v*)&Bs[(wn * 64 + j * 16 + lr) * 64 + kk + lg * 8];
#pragma unroll
            for (int i = 0; i < 2; ++i)
#pragma unroll
                for (int j = 0; j < 4; ++j)
                    acc[i][j] = __builtin_amdgcn_mfma_f32_16x16x32_bf16(aF[i], bF[j], acc[i][j], 0, 0, 0);
        }
    }
    const float* bias = (range == 0) ? q_b : (range == 1) ? k_b : v_b;
    u16* dst = (range == 0) ? outq : (range == 1) ? outk : outv;
    float scale = (range == 0) ? LOG2Ec : (range == 1) ? KSCALEc : 1.0f;
#pragma unroll
    for (int j = 0; j < 4; ++j) {
        int n = n0 + wn * 64 + j * 16 + lr;
        int nc = n & 255;
        float bv = bias[nc];
#pragma unroll
        for (int i = 0; i < 2; ++i) {
#pragma unroll
            for (int r = 0; r < 4; ++r) {
                int m = m0 + wm * 32 + i * 16 + lg * 4 + r;
                if (m >= M) continue;
                float v = (acc[i][j][r] + bv) * scale;
                u16 hv = f2bf(v);
                dst[(size_t)m * 256 + nc] = hv;
                if (range == 1) {
                    unsigned um = (unsigned)m;
                    unsigned bb = um / 2312u;
                    unsigned nr = um - bb * 2312u;
                    outkt[((size_t)(bb * NHc + (nc >> 5)) * Dc + (nc & 31)) * KTLDc + nr] = hv;
                }
            }
        }
    }
}

// ---------------- MFMA flash attention (round-16 proven): 4-wave, KT=64, swapped QK^T, raw exp2 ----------------
__global__ __launch_bounds__(256, 4) void attn_mfma_kernel(const u16* __restrict__ q,
                                                           const u16* __restrict__ k,
                                                           const u16* __restrict__ kt,
                                                           const u16* __restrict__ p,
                                                           u16* __restrict__ o)
{
    constexpr int KT = 64;
    constexpr int NT = (Nc + KT - 1) / KT;  // 37
    __shared__ __align__(16) u16 Kls[KT * 40];     // [kv][d]
    __shared__ __align__(16) u16 Ktls[32 * 88];    // [d][kv]
    __shared__ __align__(16) unsigned PW[4][16 * 36]; // per-wave packed P

    int flat = blockIdx.x;
    int grp  = flat & 31;       // (b,h) group -> XCD-local
    int qblk = flat >> 5;       // 0..36
    int b = grp >> 3, h = grp & 7;

    int t = threadIdx.x;
    int w = t >> 6, l = t & 63, lg = l >> 4, lr = l & 15;
    int q0 = qblk * 64 + w * 16;

    int qrow = q0 + lr;
    bool qtok = (qrow < NQc);
    int qrc = qrow < Nc ? qrow : Nc - 1;
    s8v qB = *(const s8v*)&q[((size_t)b * Nc + qrc) * Cc + h * Dc + lg * 8];

    s8v pqB = {0, 0, 0, 0, 0, 0, 0, 0};
    if (lg == 0 && qrow >= NQc && qrow < Nc)
        pqB = *(const s8v*)&p[((size_t)b * HWc + (qrow - NQc)) * 8];

    f32x4 accO[2] = {{0.f, 0.f, 0.f, 0.f}, {0.f, 0.f, 0.f, 0.f}};
    float lrun = 0.f;

    int srow = t >> 2, sseg = (t & 3) * 8;     // K staging
    int td = t >> 3, tks = (t & 7) * 8;        // Kt staging
    const u16* ktbase = kt + ((size_t)(b * NHc + h) * Dc + td) * KTLDc;
    const u16* pbase  = p + (size_t)b * HWc * 8;
    unsigned* PWr = &PW[w][lr * 36];
    int bsrc = lg * 20;  // broadcast source lane base

    s8v kv8 = {0,0,0,0,0,0,0,0};
    if (srow < Nc)
        kv8 = *(const s8v*)&k[((size_t)b * Nc + srow) * Cc + h * Dc + sseg];
    s8v kt8 = *(const s8v*)&ktbase[tks];

    for (int ti = 0; ti < NT; ++ti) {
        int m0 = ti * KT;
        bool tail = (ti == NT - 1);
        __syncthreads();
        *(s8v*)&Kls[srow * 40 + sseg] = kv8;
        *(s8v*)&Ktls[td * 88 + tks]   = kt8;
        __syncthreads();

        if (ti + 1 < NT) {
            int n0g = m0 + KT;
            kv8 = (s8v){0,0,0,0,0,0,0,0};
            int kvg = n0g + srow;
            if (kvg < Nc)
                kv8 = *(const s8v*)&k[((size_t)b * Nc + kvg) * Cc + h * Dc + sseg];
            kt8 = *(const s8v*)&ktbase[n0g + tks];
        }

        float sc[4][4];
#pragma unroll
        for (int cb = 0; cb < 4; ++cb) {
            s8v kA = *(s8v*)&Kls[(cb * 16 + lr) * 40 + lg * 8];
            f32x4 St = __builtin_amdgcn_mfma_f32_16x16x32_bf16(kA, qB, (f32x4){0.f,0.f,0.f,0.f}, 0, 0, 0);
            s8v pkA = {0, 0, 0, 0, 0, 0, 0, 0};
            if (lg == 0) {
                int kvr = m0 + cb * 16 + lr;
                if (kvr >= NQc && kvr < Nc)
                    pkA = *(const s8v*)&pbase[(size_t)(kvr - NQc) * 8];
            }
            f32x4 Mv = __builtin_amdgcn_mfma_f32_16x16x32_bf16(pkA, pqB, (f32x4){0.f,0.f,0.f,0.f}, 0, 0, 0);
            bool ktok = (ti == 0 && cb == 0 && lg < 2);  // kv-row < 8
#pragma unroll
            for (int j = 0; j < 4; ++j) {
                float mval = (qtok || ktok) ? 1.f : Mv[j];
                sc[cb][j] = St[j] * mval;
            }
        }
        // softmax numerator: q pre-scaled by log2e -> raw v_exp_f32 (fixed shift 0, |S|<=~2)
        float tsum = 0.f;
#pragma unroll
        for (int cb = 0; cb < 4; ++cb)
#pragma unroll
            for (int j = 0; j < 4; ++j) {
                float ev = fast_exp2(sc[cb][j]);
                if (tail && (cb != 0 || lg >= 2)) ev = 0.f;  // kv >= Nc
                sc[cb][j] = ev;
                tsum += ev;
            }
        tsum += __shfl_xor(tsum, 16);
        tsum += __shfl_xor(tsum, 32);
        lrun += tsum;
#pragma unroll
        for (int cb = 0; cb < 4; ++cb) {
            uint2 pk2;
            pk2.x = cvtpk2(sc[cb][0], sc[cb][1]);
            pk2.y = cvtpk2(sc[cb][2], sc[cb][3]);
            *(uint2*)&PWr[8 * cb + 2 * lg] = pk2;
        }
#pragma unroll
        for (int kc = 0; kc < 2; ++kc) {
            s8v pA = *(s8v*)&PWr[16 * kc + 4 * lg];
#pragma unroll
            for (int db = 0; db < 2; ++db) {
                s8v vB = *(s8v*)&Ktls[(db * 16 + lr) * 88 + kc * 32 + lg * 8];
                accO[db] = __builtin_amdgcn_mfma_f32_16x16x32_bf16(pA, vB, accO[db], 0, 0, 0);
            }
        }
    }

    float lb[4];
#pragma unroll
    for (int j = 0; j < 4; ++j) lb[j] = __shfl(lrun, bsrc + j);
#pragma unroll
    for (int db = 0; db < 2; ++db)
#pragma unroll
        for (int j = 0; j < 4; ++j) {
            int rowg = q0 + lg * 4 + j;
            if (rowg < Nc)
                o[((size_t)b * Nc + rowg) * Cc + h * Dc + db * 16 + lr] = f2bf(accO[db][j] / lb[j]);
        }
}

extern "C" void kernel_launch(void* const* d_in, const int* in_sizes, int n_in,
                              void* d_out, int out_size, void* d_ws, size_t ws_size,
                              hipStream_t stream)
{
    const float* x       = (const float*)d_in[0];
    const float* queries = (const float*)d_in[1];
    const int*   epoch   = (const int*)d_in[2];
    const float* pos_w   = (const float*)d_in[3];
    const float* pos_b   = (const float*)d_in[4];
    const float* ln1_g   = (const float*)d_in[5];
    const float* ln1_b   = (const float*)d_in[6];
    const float* q_w     = (const float*)d_in[7];
    const float* q_b     = (const float*)d_in[8];
    const float* k_w     = (const float*)d_in[9];
    const float* k_b     = (const float*)d_in[10];
    const float* v_w     = (const float*)d_in[11];
    const float* v_b     = (const float*)d_in[12];
    const float* lepe_w  = (const float*)d_in[13];
    const float* lepe_b  = (const float*)d_in[14];
    const float* out_w   = (const float*)d_in[15];
    const float* out_b   = (const float*)d_in[16];
    const float* ln2_g   = (const float*)d_in[17];
    const float* ln2_b   = (const float*)d_in[18];
    const float* fc1_w   = (const float*)d_in[19];
    const float* fc1_b   = (const float*)d_in[20];
    const float* fc2_w   = (const float*)d_in[21];
    const float* fc2_b   = (const float*)d_in[22];

    float* ws = (float*)d_ws;
    float* xq  = ws;                        // f32, 2,367,488
    u16*  ybf  = (u16*)(ws + 2367488);      // bf16 2,367,488 (1,183,744 slots)
    u16*  qbf  = (u16*)(ws + 3551232);      // bf16 2,367,488
    u16*  kbf  = (u16*)(ws + 4734976);      // bf16 2,367,488
    u16*  ktbf = (u16*)(ws + 5918720);      // bf16 4*8*32*2368 = 2,424,832 (1,212,416 slots)
    u16*  pbf  = (u16*)(ws + 7131136);      // bf16 73,728 (36,864 slots)
    u16*  obf  = (u16*)(ws + 7168000);      // bf16 2,367,488
    u16*  vbf  = (u16*)(ws + 8351744);      // bf16 2,367,488
    u16*  wbf  = (u16*)(ws + 9535488);      // bf16 786,432 (weights)
    u16*  ffn  = qbf;                       // fc1 act aliases qbf..obf (dead by then)

    u16* w_o  = wbf + 196608;
    u16* w_f1 = wbf + 262144;
    u16* w_f2 = wbf + 524288;

    fused_pre_kernel<<<9248 + 768 + 224, 256, 0, stream>>>(
        x, queries, epoch, pos_w, pos_b, ln1_g, ln1_b,
        q_w, k_w, v_w, out_w, fc1_w, fc2_w,
        xq, ybf, pbf, wbf, ktbf);

    mfma_gemm_qkv64_kernel<<<dim3(6, 145), 256, 0, stream>>>(ybf, wbf, q_b, k_b, v_b, qbf, kbf, ktbf, vbf);

    attn_mfma_kernel<<<1184, 256, 0, stream>>>(qbf, kbf, ktbf, pbf, obf);

    // fused lepe + out-proj + residual + LN2 (replaces lepe dispatch + oln)
    mfma_gemm_oln_kernel<<<289, 256, 0, stream>>>(obf, vbf, lepe_w, lepe_b,
                                                  w_o, out_b, xq, ln2_g, ln2_b, ybf);

    mfma_gemm64_kernel<1,0,1><<<dim3(8, 145), 256, 0, stream>>>(ybf, w_f1, fc1_b, nullptr, nullptr, ffn, MRc, 1024, 256, 1.0f);
    mfma_gemm64_kernel<0,1,3><<<dim3(2, 145), 256, 0, stream>>>(ffn, w_f2, fc2_b, xq, (float*)d_out, nullptr, MRc, 256, 1024, 1.0f);
}

// Round 21
// 205.177 us; speedup vs baseline: 1.0968x; 1.0968x over previous
//
#include <hip/hip_runtime.h>
#include <hip/hip_bf16.h>
#include <math.h>

typedef unsigned short u16;
constexpr int Bc = 4, Hc = 48, Wc = 48, Cc = 256;
constexpr int NQc = 8, HWc = 2304, Nc = 2312, NHc = 8, Dc = 32, FFNc = 1024;
constexpr int MRc = Bc * Nc; // 9248
constexpr int KTLDc = 2368;  // padded kv length for transposed K (37*64)
constexpr float KSCALEc = 0.17677669529663687f; // (256/8)^-0.5
constexpr float LOG2Ec  = 1.4426950408889634f;

typedef __attribute__((ext_vector_type(8))) short s8v;
typedef __attribute__((ext_vector_type(4))) float f32x4;

__device__ __forceinline__ u16 f2bf(float f) {
    union { __hip_bfloat16 h; u16 u; } c;
    c.h = __float2bfloat16(f);
    return c.u;
}
__device__ __forceinline__ float bf2f(u16 u) {
    return __uint_as_float(((unsigned)u) << 16);
}
__device__ __forceinline__ unsigned cvtpk2(float lo, float hi) {
    unsigned r;
    asm("v_cvt_pk_bf16_f32 %0, %1, %2" : "=v"(r) : "v"(lo), "v"(hi));
    return r;
}
// raw v_exp_f32 (2^x), no OCML range fixup
__device__ __forceinline__ float fast_exp2(float x) {
    float r;
    asm("v_exp_f32 %0, %1" : "=v"(r) : "v"(x));
    return r;
}
// async global->LDS, 16B per lane; lds dest is wave-uniform base + lane*16
__device__ __forceinline__ void gload16(const void* g, void* l) {
    __builtin_amdgcn_global_load_lds((const __attribute__((address_space(1))) void*)g,
                                     (__attribute__((address_space(3))) void*)l, 16, 0, 0);
}

// ---------------- fused: pre (pos conv + LN1 + region softmax) / weight convert / kt pad-zero ----------------
__global__ __launch_bounds__(256) void fused_pre_kernel(
    const float* __restrict__ x, const float* __restrict__ queries, const int* __restrict__ epoch,
    const float* __restrict__ pos_w, const float* __restrict__ pos_b,
    const float* __restrict__ ln_g, const float* __restrict__ ln_b,
    const float* __restrict__ qw, const float* __restrict__ kw, const float* __restrict__ vw,
    const float* __restrict__ ow, const float* __restrict__ f1, const float* __restrict__ f2,
    float* __restrict__ xq, u16* __restrict__ ybf, u16* __restrict__ pbf,
    u16* __restrict__ wbf, u16* __restrict__ kt)
{
    int bi = blockIdx.x;
    if (bi >= 9248) {
        int bj = bi - 9248;
        if (bj < 768) {
            int i4 = bj * 256 + threadIdx.x;
            int idx = i4 * 4;
            const float* src; int off;
            if      (idx < 65536)  { src = qw; off = idx; }
            else if (idx < 131072) { src = kw; off = idx - 65536; }
            else if (idx < 196608) { src = vw; off = idx - 131072; }
            else if (idx < 262144) { src = ow; off = idx - 196608; }
            else if (idx < 524288) { src = f1; off = idx - 262144; }
            else                   { src = f2; off = idx - 524288; }
            float4 v = *(const float4*)(src + off);
            ushort4 o;
            o.x = f2bf(v.x); o.y = f2bf(v.y); o.z = f2bf(v.z); o.w = f2bf(v.w);
            *(ushort4*)(wbf + idx) = o;
        } else {
            int idx = (bj - 768) * 256 + threadIdx.x;  // 1024 rows * 56 pad cols
            if (idx < 1024 * 56) {
                int row = idx / 56, col = idx - row * 56;
                kt[(size_t)row * KTLDc + 2312 + col] = 0;
            }
        }
        return;
    }
    int blk = bi;                        // 0..9247
    int b = blk / Nc, n = blk - b * Nc;
    int c = threadIdx.x;
    bool sp = (n >= NQc);
    float val;
    if (sp) {
        int s = n - NQc;
        int hh = s / Wc, ww = s - hh * Wc;
        float acc = pos_b[c];
        float center = x[((b * Hc + hh) * Wc + ww) * Cc + c];
#pragma unroll
        for (int kh = 0; kh < 3; ++kh) {
            int yy = hh + kh - 1;
            if (yy < 0 || yy >= Hc) continue;
#pragma unroll
            for (int kw2 = 0; kw2 < 3; ++kw2) {
                int xx = ww + kw2 - 1;
                if (xx < 0 || xx >= Wc) continue;
                acc += x[((b * Hc + yy) * Wc + xx) * Cc + c] * pos_w[(kh * 3 + kw2) * Cc + c];
            }
        }
        val = center + acc;
    } else {
        val = queries[(b * NQc + n) * Cc + c];
    }
    xq[(size_t)blk * Cc + c] = val;

    float pq[8];
#pragma unroll
    for (int qi = 0; qi < 8; ++qi)
        pq[qi] = sp ? val * queries[(b * NQc + qi) * Cc + c] : 0.f;
    float r0 = val, r1 = val * val;
#pragma unroll
    for (int off = 32; off; off >>= 1) {
        r0 += __shfl_xor(r0, off);
        r1 += __shfl_xor(r1, off);
#pragma unroll
        for (int qi = 0; qi < 8; ++qi) pq[qi] += __shfl_xor(pq[qi], off);
    }
    __shared__ float red[4][10];
    __shared__ float fin[10];
    int wv = c >> 6, ln = c & 63;
    if (ln == 0) {
        red[wv][0] = r0; red[wv][1] = r1;
#pragma unroll
        for (int qi = 0; qi < 8; ++qi) red[wv][2 + qi] = pq[qi];
    }
    __syncthreads();
    if (c < 10) fin[c] = red[0][c] + red[1][c] + red[2][c] + red[3][c];
    __syncthreads();
    float mean = fin[0] * (1.0f / 256.0f);
    float var  = fin[1] * (1.0f / 256.0f) - mean * mean;
    float inv  = rsqrtf(var + 1e-6f);
    ybf[(size_t)blk * Cc + c] = f2bf((val - mean) * inv * ln_g[c] + ln_b[c]);

    if (sp && c < 8) {
        float it = 1.0f / (2.0f * powf(0.05f, (float)(*epoch) / 200.0f));
        float mx = -1e30f;
        float lg[8];
#pragma unroll
        for (int qi = 0; qi < 8; ++qi) { lg[qi] = fin[2 + qi] * it; mx = fmaxf(mx, lg[qi]); }
        float s = 0.f, mine = 0.f;
#pragma unroll
        for (int qi = 0; qi < 8; ++qi) {
            float ev = __expf(lg[qi] - mx);
            s += ev;
            if (qi == c) mine = ev;
        }
        pbf[((size_t)b * HWc + (n - NQc)) * 8 + c] = f2bf(mine / s);
    }
}

// ---------------- 64x128-tile GEMM (high block-count variant) ----------------
// OMODE: 0=f32 out, 1=bf16 out, 3=f32 out permuted to d_out layout (N==256)
template <int ACT, int RESID, int OMODE>
__global__ __launch_bounds__(256) void mfma_gemm64_kernel(
    const u16* __restrict__ A, const u16* __restrict__ W,
    const float* __restrict__ bias, const float* resid,
    float* outF, u16* outB, int M, int N, int K, float scale)
{
    __shared__ u16 As[64 * 64];
    __shared__ u16 Bs[128 * 64];
    int t = threadIdx.x;
    int w = t >> 6, l = t & 63, lg = l >> 4, lr = l & 15;
    int wm = w >> 1, wn = w & 1;
    int m0 = blockIdx.y * 64, n0 = blockIdx.x * 128;
    f32x4 acc[2][4] = {};
    int lrow = l >> 3, lchunk = (l & 7) * 8;
    for (int k0 = 0; k0 < K; k0 += 64) {
        __syncthreads();
#pragma unroll
        for (int c = 0; c < 2; ++c) {
            int ar = m0 + w * 16 + c * 8 + lrow;
            if (ar >= M) ar = M - 1;
            gload16(A + (size_t)ar * K + k0 + lchunk, As + (w * 16 + c * 8) * 64);
        }
#pragma unroll
        for (int c = 0; c < 4; ++c) {
            int br = n0 + w * 32 + c * 8 + lrow;
            gload16(W + (size_t)br * K + k0 + lchunk, Bs + (w * 32 + c * 8) * 64);
        }
        __syncthreads();
#pragma unroll
        for (int kk = 0; kk < 64; kk += 32) {
            s8v aF[2], bF[4];
#pragma unroll
            for (int i = 0; i < 2; ++i)
                aF[i] = *(s8v*)&As[(wm * 32 + i * 16 + lr) * 64 + kk + lg * 8];
#pragma unroll
            for (int j = 0; j < 4; ++j)
                bF[j] = *(s8v*)&Bs[(wn * 64 + j * 16 + lr) * 64 + kk + lg * 8];
#pragma unroll
            for (int i = 0; i < 2; ++i)
#pragma unroll
                for (int j = 0; j < 4; ++j)
                    acc[i][j] = __builtin_amdgcn_mfma_f32_16x16x32_bf16(aF[i], bF[j], acc[i][j], 0, 0, 0);
        }
    }
#pragma unroll
    for (int j = 0; j < 4; ++j) {
        int n = n0 + wn * 64 + j * 16 + lr;
        float bv = bias[n];
#pragma unroll
        for (int i = 0; i < 2; ++i) {
#pragma unroll
            for (int r = 0; r < 4; ++r) {
                int m = m0 + wm * 32 + i * 16 + lg * 4 + r;
                if (m >= M) continue;
                float v = (acc[i][j][r] + bv) * scale;
                if (ACT == 1) {
                    float e = fast_exp2(2.302118f * (v + 0.044715f * v * v * v));
                    v = v * e * __builtin_amdgcn_rcpf(e + 1.0f);
                }
                if (RESID) v += resid[(size_t)m * N + n];
                if (OMODE == 0) {
                    outF[(size_t)m * N + n] = v;
                } else if (OMODE == 3) {
                    unsigned bb2 = (unsigned)m / 2312u;
                    unsigned tok = (unsigned)m - bb2 * 2312u;
                    size_t ob = (tok >= 8) ? (((size_t)(bb2 * 2304 + tok - 8)) << 8)
                                           : ((size_t)2359296 + (((size_t)(bb2 * 8 + tok)) << 8));
                    outF[ob + n] = v;
                } else {
                    outB[(size_t)m * N + n] = f2bf(v);
                }
            }
        }
    }
}

// ---------------- fused out-proj + residual + LN2: 32x256 tile (full rows), 289 blocks ----------------
__global__ __launch_bounds__(256) void mfma_gemm_oln_kernel(
    const u16* __restrict__ A, const u16* __restrict__ W,
    const float* __restrict__ bias, float* __restrict__ xq,
    const float* __restrict__ g, const float* __restrict__ bb,
    u16* __restrict__ ybf)
{
    const int K = Cc;
    __shared__ u16 As[32 * 64];     // 4 KB
    __shared__ u16 Bs[256 * 64];    // 32 KB
    __shared__ float R[32][4][2];   // per-row per-wave partial sum/sumsq
    __shared__ float MI[32][2];     // per-row mean, inv
    int t = threadIdx.x;
    int w = t >> 6, l = t & 63, lg = l >> 4, lr = l & 15;
    int m0 = blockIdx.x * 32;
    f32x4 acc[2][4] = {};
    int lrow = l >> 3, lchunk = (l & 7) * 8;
    for (int k0 = 0; k0 < K; k0 += 64) {
        __syncthreads();
        gload16(A + (size_t)(m0 + w * 8 + lrow) * K + k0 + lchunk, As + (w * 8) * 64);
#pragma unroll
        for (int c = 0; c < 8; ++c)
            gload16(W + (size_t)(w * 64 + c * 8 + lrow) * K + k0 + lchunk, Bs + (w * 64 + c * 8) * 64);
        __syncthreads();
#pragma unroll
        for (int kk = 0; kk < 64; kk += 32) {
            s8v aF[2], bF[4];
#pragma unroll
            for (int i = 0; i < 2; ++i)
                aF[i] = *(s8v*)&As[(i * 16 + lr) * 64 + kk + lg * 8];
#pragma unroll
            for (int j = 0; j < 4; ++j)
                bF[j] = *(s8v*)&Bs[(w * 64 + j * 16 + lr) * 64 + kk + lg * 8];
#pragma unroll
            for (int i = 0; i < 2; ++i)
#pragma unroll
                for (int j = 0; j < 4; ++j)
                    acc[i][j] = __builtin_amdgcn_mfma_f32_16x16x32_bf16(aF[i], bF[j], acc[i][j], 0, 0, 0);
        }
    }
    float s[2][4], ss[2][4];
#pragma unroll
    for (int i = 0; i < 2; ++i)
#pragma unroll
        for (int r = 0; r < 4; ++r) { s[i][r] = 0.f; ss[i][r] = 0.f; }
#pragma unroll
    for (int j = 0; j < 4; ++j) {
        int n = w * 64 + j * 16 + lr;
        float bv = bias[n];
#pragma unroll
        for (int i = 0; i < 2; ++i) {
#pragma unroll
            for (int r = 0; r < 4; ++r) {
                int m = m0 + i * 16 + lg * 4 + r;
                float v = acc[i][j][r] + bv + xq[(size_t)m * Cc + n];
                acc[i][j][r] = v;
                xq[(size_t)m * Cc + n] = v;
                s[i][r] += v;
                ss[i][r] += v * v;
            }
        }
    }
#pragma unroll
    for (int i = 0; i < 2; ++i)
#pragma unroll
        for (int r = 0; r < 4; ++r) {
#pragma unroll
            for (int off = 1; off < 16; off <<= 1) {
                s[i][r]  += __shfl_xor(s[i][r], off);
                ss[i][r] += __shfl_xor(ss[i][r], off);
            }
        }
    __syncthreads();
    if (lr == 0) {
#pragma unroll
        for (int i = 0; i < 2; ++i)
#pragma unroll
            for (int r = 0; r < 4; ++r) {
                int row = i * 16 + lg * 4 + r;
                R[row][w][0] = s[i][r];
                R[row][w][1] = ss[i][r];
            }
    }
    __syncthreads();
    if (t < 32) {
        float tot  = R[t][0][0] + R[t][1][0] + R[t][2][0] + R[t][3][0];
        float tots = R[t][0][1] + R[t][1][1] + R[t][2][1] + R[t][3][1];
        float mean = tot * (1.0f / 256.0f);
        float var  = tots * (1.0f / 256.0f) - mean * mean;
        MI[t][0] = mean;
        MI[t][1] = rsqrtf(var + 1e-6f);
    }
    __syncthreads();
#pragma unroll
    for (int j = 0; j < 4; ++j) {
        int n = w * 64 + j * 16 + lr;
        float gv = g[n], bbv = bb[n];
#pragma unroll
        for (int i = 0; i < 2; ++i) {
#pragma unroll
            for (int r = 0; r < 4; ++r) {
                int row = i * 16 + lg * 4 + r;
                float mean = MI[row][0], inv = MI[row][1];
                int m = m0 + row;
                ybf[(size_t)m * Cc + n] = f2bf((acc[i][j][r] - mean) * inv * gv + bbv);
            }
        }
    }
}

// ---------------- fused QKV GEMM, 64x128 tile (870 blocks), N=768, K=256 ----------------
__global__ __launch_bounds__(256) void mfma_gemm_qkv64_kernel(
    const u16* __restrict__ A, const u16* __restrict__ W,
    const float* __restrict__ q_b, const float* __restrict__ k_b, const float* __restrict__ v_b,
    u16* __restrict__ outq, u16* __restrict__ outk, u16* __restrict__ outkt, u16* __restrict__ outv)
{
    const int M = MRc, K = Cc;
    __shared__ u16 As[64 * 64];
    __shared__ u16 Bs[128 * 64];
    int t = threadIdx.x;
    int w = t >> 6, l = t & 63, lg = l >> 4, lr = l & 15;
    int wm = w >> 1, wn = w & 1;
    int m0 = blockIdx.y * 64, n0 = blockIdx.x * 128;
    int range = n0 >> 8;  // n0 in {0,128,256,384,512,640} -> 0,0,1,1,2,2
    f32x4 acc[2][4] = {};
    int lrow = l >> 3, lchunk = (l & 7) * 8;
    for (int k0 = 0; k0 < K; k0 += 64) {
        __syncthreads();
#pragma unroll
        for (int c = 0; c < 2; ++c) {
            int ar = m0 + w * 16 + c * 8 + lrow;
            if (ar >= M) ar = M - 1;
            gload16(A + (size_t)ar * K + k0 + lchunk, As + (w * 16 + c * 8) * 64);
        }
#pragma unroll
        for (int c = 0; c < 4; ++c) {
            int br = n0 + w * 32 + c * 8 + lrow;
            gload16(W + (size_t)br * K + k0 + lchunk, Bs + (w * 32 + c * 8) * 64);
        }
        __syncthreads();
#pragma unroll
        for (int kk = 0; kk < 64; kk += 32) {
            s8v aF[2], bF[4];
#pragma unroll
            for (int i = 0; i < 2; ++i)
                aF[i] = *(s8v*)&As[(wm * 32 + i * 16 + lr) * 64 + kk + lg * 8];
#pragma unroll
            for (int j = 0; j < 4; ++j)
                bF[j] = *(s8v*)&Bs[(wn * 64 + j * 16 + lr) * 64 + kk + lg * 8];
#pragma unroll
            for (int i = 0; i < 2; ++i)
#pragma unroll
                for (int j = 0; j < 4; ++j)
                    acc[i][j] = __builtin_amdgcn_mfma_f32_16x16x32_bf16(aF[i], bF[j], acc[i][j], 0, 0, 0);
        }
    }
    const float* bias = (range == 0) ? q_b : (range == 1) ? k_b : v_b;
    u16* dst = (range == 0) ? outq : (range == 1) ? outk : outv;
    float scale = (range == 0) ? LOG2Ec : (range == 1) ? KSCALEc : 1.0f;
#pragma unroll
    for (int j = 0; j < 4; ++j) {
        int n = n0 + wn * 64 + j * 16 + lr;
        int nc = n & 255;
        float bv = bias[nc];
#pragma unroll
        for (int i = 0; i < 2; ++i) {
#pragma unroll
            for (int r = 0; r < 4; ++r) {
                int m = m0 + wm * 32 + i * 16 + lg * 4 + r;
                if (m >= M) continue;
                float v = (acc[i][j][r] + bv) * scale;
                u16 hv = f2bf(v);
                dst[(size_t)m * 256 + nc] = hv;
                if (range == 1) {
                    unsigned um = (unsigned)m;
                    unsigned bb = um / 2312u;
                    unsigned nr = um - bb * 2312u;
                    outkt[((size_t)(bb * NHc + (nc >> 5)) * Dc + (nc & 31)) * KTLDc + nr] = hv;
                }
            }
        }
    }
}

// ---------------- lepe dwconv 5x5 on v (bf16), vectorized 8 ch/thread, added into o ----------------
__global__ void lepe_conv_add_kernel(const u16* __restrict__ v, const float* __restrict__ w,
                                     const float* __restrict__ bias, u16* __restrict__ o)
{
    int idx = blockIdx.x * 256 + threadIdx.x;   // Bc*HWc*32 = 294912
    if (idx >= Bc * HWc * 32) return;
    int cg = (idx & 31) * 8;
    int sp = idx >> 5;
    int ww = sp % Wc;
    int t2 = sp / Wc;
    int hh = t2 % Hc;
    int b  = t2 / Hc;
    float acc[8];
#pragma unroll
    for (int i = 0; i < 8; ++i) acc[i] = bias[cg + i];
#pragma unroll
    for (int kh = 0; kh < 5; ++kh) {
        int yy = hh + kh - 2;
        if (yy < 0 || yy >= Hc) continue;
#pragma unroll
        for (int kw = 0; kw < 5; ++kw) {
            int xx = ww + kw - 2;
            if (xx < 0 || xx >= Wc) continue;
            union { s8v s; u16 u[8]; } uv;
            uv.s = *(const s8v*)&v[((size_t)b * Nc + NQc + yy * Wc + xx) * Cc + cg];
            const float4* wp = (const float4*)&w[(kh * 5 + kw) * Cc + cg];
            float4 w0 = wp[0], w1 = wp[1];
            acc[0] += bf2f(uv.u[0]) * w0.x;
            acc[1] += bf2f(uv.u[1]) * w0.y;
            acc[2] += bf2f(uv.u[2]) * w0.z;
            acc[3] += bf2f(uv.u[3]) * w0.w;
            acc[4] += bf2f(uv.u[4]) * w1.x;
            acc[5] += bf2f(uv.u[5]) * w1.y;
            acc[6] += bf2f(uv.u[6]) * w1.z;
            acc[7] += bf2f(uv.u[7]) * w1.w;
        }
    }
    size_t oi = ((size_t)b * Nc + NQc + hh * Wc + ww) * Cc + cg;
    union { s8v s; u16 u[8]; } ov, res;
    ov.s = *(const s8v*)&o[oi];
#pragma unroll
    for (int i = 0; i < 8; ++i) res.u[i] = f2bf(bf2f(ov.u[i]) + acc[i]);
    *(s8v*)&o[oi] = res.s;
}

// ---------------- MFMA flash attention (round-16 proven): 4-wave, KT=64, swapped QK^T, raw exp2 ----------------
__global__ __launch_bounds__(256, 4) void attn_mfma_kernel(const u16* __restrict__ q,
                                                           const u16* __restrict__ k,
                                                           const u16* __restrict__ kt,
                                                           const u16* __restrict__ p,
                                                           u16* __restrict__ o)
{
    constexpr int KT = 64;
    constexpr int NT = (Nc + KT - 1) / KT;  // 37
    __shared__ __align__(16) u16 Kls[KT * 40];     // [kv][d]
    __shared__ __align__(16) u16 Ktls[32 * 88];    // [d][kv]
    __shared__ __align__(16) unsigned PW[4][16 * 36]; // per-wave packed P

    int flat = blockIdx.x;
    int grp  = flat & 31;       // (b,h) group -> XCD-local
    int qblk = flat >> 5;       // 0..36
    int b = grp >> 3, h = grp & 7;

    int t = threadIdx.x;
    int w = t >> 6, l = t & 63, lg = l >> 4, lr = l & 15;
    int q0 = qblk * 64 + w * 16;

    int qrow = q0 + lr;
    bool qtok = (qrow < NQc);
    int qrc = qrow < Nc ? qrow : Nc - 1;
    s8v qB = *(const s8v*)&q[((size_t)b * Nc + qrc) * Cc + h * Dc + lg * 8];

    s8v pqB = {0, 0, 0, 0, 0, 0, 0, 0};
    if (lg == 0 && qrow >= NQc && qrow < Nc)
        pqB = *(const s8v*)&p[((size_t)b * HWc + (qrow - NQc)) * 8];

    f32x4 accO[2] = {{0.f, 0.f, 0.f, 0.f}, {0.f, 0.f, 0.f, 0.f}};
    float lrun = 0.f;

    int srow = t >> 2, sseg = (t & 3) * 8;     // K staging
    int td = t >> 3, tks = (t & 7) * 8;        // Kt staging
    const u16* ktbase = kt + ((size_t)(b * NHc + h) * Dc + td) * KTLDc;
    const u16* pbase  = p + (size_t)b * HWc * 8;
    unsigned* PWr = &PW[w][lr * 36];
    int bsrc = lg * 20;  // broadcast source lane base

    s8v kv8 = {0,0,0,0,0,0,0,0};
    if (srow < Nc)
        kv8 = *(const s8v*)&k[((size_t)b * Nc + srow) * Cc + h * Dc + sseg];
    s8v kt8 = *(const s8v*)&ktbase[tks];

    for (int ti = 0; ti < NT; ++ti) {
        int m0 = ti * KT;
        bool tail = (ti == NT - 1);
        __syncthreads();
        *(s8v*)&Kls[srow * 40 + sseg] = kv8;
        *(s8v*)&Ktls[td * 88 + tks]   = kt8;
        __syncthreads();

        if (ti + 1 < NT) {
            int n0g = m0 + KT;
            kv8 = (s8v){0,0,0,0,0,0,0,0};
            int kvg = n0g + srow;
            if (kvg < Nc)
                kv8 = *(const s8v*)&k[((size_t)b * Nc + kvg) * Cc + h * Dc + sseg];
            kt8 = *(const s8v*)&ktbase[n0g + tks];
        }

        float sc[4][4];
#pragma unroll
        for (int cb = 0; cb < 4; ++cb) {
            s8v kA = *(s8v*)&Kls[(cb * 16 + lr) * 40 + lg * 8];
            f32x4 St = __builtin_amdgcn_mfma_f32_16x16x32_bf16(kA, qB, (f32x4){0.f,0.f,0.f,0.f}, 0, 0, 0);
            s8v pkA = {0, 0, 0, 0, 0, 0, 0, 0};
            if (lg == 0) {
                int kvr = m0 + cb * 16 + lr;
                if (kvr >= NQc && kvr < Nc)
                    pkA = *(const s8v*)&pbase[(size_t)(kvr - NQc) * 8];
            }
            f32x4 Mv = __builtin_amdgcn_mfma_f32_16x16x32_bf16(pkA, pqB, (f32x4){0.f,0.f,0.f,0.f}, 0, 0, 0);
            bool ktok = (ti == 0 && cb == 0 && lg < 2);  // kv-row < 8
#pragma unroll
            for (int j = 0; j < 4; ++j) {
                float mval = (qtok || ktok) ? 1.f : Mv[j];
                sc[cb][j] = St[j] * mval;
            }
        }
        // softmax numerator: q pre-scaled by log2e -> raw v_exp_f32 (fixed shift 0, |S|<=~2)
        float tsum = 0.f;
#pragma unroll
        for (int cb = 0; cb < 4; ++cb)
#pragma unroll
            for (int j = 0; j < 4; ++j) {
                float ev = fast_exp2(sc[cb][j]);
                if (tail && (cb != 0 || lg >= 2)) ev = 0.f;  // kv >= Nc
                sc[cb][j] = ev;
                tsum += ev;
            }
        tsum += __shfl_xor(tsum, 16);
        tsum += __shfl_xor(tsum, 32);
        lrun += tsum;
#pragma unroll
        for (int cb = 0; cb < 4; ++cb) {
            uint2 pk2;
            pk2.x = cvtpk2(sc[cb][0], sc[cb][1]);
            pk2.y = cvtpk2(sc[cb][2], sc[cb][3]);
            *(uint2*)&PWr[8 * cb + 2 * lg] = pk2;
        }
#pragma unroll
        for (int kc = 0; kc < 2; ++kc) {
            s8v pA = *(s8v*)&PWr[16 * kc + 4 * lg];
#pragma unroll
            for (int db = 0; db < 2; ++db) {
                s8v vB = *(s8v*)&Ktls[(db * 16 + lr) * 88 + kc * 32 + lg * 8];
                accO[db] = __builtin_amdgcn_mfma_f32_16x16x32_bf16(pA, vB, accO[db], 0, 0, 0);
            }
        }
    }

    float lb[4];
#pragma unroll
    for (int j = 0; j < 4; ++j) lb[j] = __shfl(lrun, bsrc + j);
#pragma unroll
    for (int db = 0; db < 2; ++db)
#pragma unroll
        for (int j = 0; j < 4; ++j) {
            int rowg = q0 + lg * 4 + j;
            if (rowg < Nc)
                o[((size_t)b * Nc + rowg) * Cc + h * Dc + db * 16 + lr] = f2bf(accO[db][j] / lb[j]);
        }
}

extern "C" void kernel_launch(void* const* d_in, const int* in_sizes, int n_in,
                              void* d_out, int out_size, void* d_ws, size_t ws_size,
                              hipStream_t stream)
{
    const float* x       = (const float*)d_in[0];
    const float* queries = (const float*)d_in[1];
    const int*   epoch   = (const int*)d_in[2];
    const float* pos_w   = (const float*)d_in[3];
    const float* pos_b   = (const float*)d_in[4];
    const float* ln1_g   = (const float*)d_in[5];
    const float* ln1_b   = (const float*)d_in[6];
    const float* q_w     = (const float*)d_in[7];
    const float* q_b     = (const float*)d_in[8];
    const float* k_w     = (const float*)d_in[9];
    const float* k_b     = (const float*)d_in[10];
    const float* v_w     = (const float*)d_in[11];
    const float* v_b     = (const float*)d_in[12];
    const float* lepe_w  = (const float*)d_in[13];
    const float* lepe_b  = (const float*)d_in[14];
    const float* out_w   = (const float*)d_in[15];
    const float* out_b   = (const float*)d_in[16];
    const float* ln2_g   = (const float*)d_in[17];
    const float* ln2_b   = (const float*)d_in[18];
    const float* fc1_w   = (const float*)d_in[19];
    const float* fc1_b   = (const float*)d_in[20];
    const float* fc2_w   = (const float*)d_in[21];
    const float* fc2_b   = (const float*)d_in[22];

    float* ws = (float*)d_ws;
    float* xq  = ws;                        // f32, 2,367,488
    u16*  ybf  = (u16*)(ws + 2367488);      // bf16 2,367,488 (1,183,744 slots)
    u16*  qbf  = (u16*)(ws + 3551232);      // bf16 2,367,488
    u16*  kbf  = (u16*)(ws + 4734976);      // bf16 2,367,488
    u16*  ktbf = (u16*)(ws + 5918720);      // bf16 4*8*32*2368 = 2,424,832 (1,212,416 slots)
    u16*  pbf  = (u16*)(ws + 7131136);      // bf16 73,728 (36,864 slots)
    u16*  obf  = (u16*)(ws + 7168000);      // bf16 2,367,488
    u16*  vbf  = (u16*)(ws + 8351744);      // bf16 2,367,488
    u16*  wbf  = (u16*)(ws + 9535488);      // bf16 786,432 (weights)
    u16*  ffn  = qbf;                       // fc1 act aliases qbf..obf (dead by then)

    u16* w_o  = wbf + 196608;
    u16* w_f1 = wbf + 262144;
    u16* w_f2 = wbf + 524288;

    fused_pre_kernel<<<9248 + 768 + 224, 256, 0, stream>>>(
        x, queries, epoch, pos_w, pos_b, ln1_g, ln1_b,
        q_w, k_w, v_w, out_w, fc1_w, fc2_w,
        xq, ybf, pbf, wbf, ktbf);

    mfma_gemm_qkv64_kernel<<<dim3(6, 145), 256, 0, stream>>>(ybf, wbf, q_b, k_b, v_b, qbf, kbf, ktbf, vbf);

    attn_mfma_kernel<<<1184, 256, 0, stream>>>(qbf, kbf, ktbf, pbf, obf);
    lepe_conv_add_kernel<<<1152, 256, 0, stream>>>(vbf, lepe_w, lepe_b, obf);

    mfma_gemm_oln_kernel<<<289, 256, 0, stream>>>(obf, w_o, out_b, xq, ln2_g, ln2_b, ybf);

    mfma_gemm64_kernel<1,0,1><<<dim3(8, 145), 256, 0, stream>>>(ybf, w_f1, fc1_b, nullptr, nullptr, ffn, MRc, 1024, 256, 1.0f);
    mfma_gemm64_kernel<0,1,3><<<dim3(2, 145), 256, 0, stream>>>(ffn, w_f2, fc2_b, xq, (float*)d_out, nullptr, MRc, 256, 1024, 1.0f);
}

// Round 22
// 194.692 us; speedup vs baseline: 1.1559x; 1.0539x over previous
//
#include <hip/hip_runtime.h>
#include <hip/hip_bf16.h>
#include <math.h>

typedef unsigned short u16;
constexpr int Bc = 4, Hc = 48, Wc = 48, Cc = 256;
constexpr int NQc = 8, HWc = 2304, Nc = 2312, NHc = 8, Dc = 32, FFNc = 1024;
constexpr int MRc = Bc * Nc; // 9248
constexpr int KTLDc = 2368;  // padded kv length for transposed K (37*64)
constexpr float KSCALEc = 0.17677669529663687f; // (256/8)^-0.5
constexpr float LOG2Ec  = 1.4426950408889634f;

typedef __attribute__((ext_vector_type(8))) short s8v;
typedef __attribute__((ext_vector_type(4))) float f32x4;

__device__ __forceinline__ u16 f2bf(float f) {
    union { __hip_bfloat16 h; u16 u; } c;
    c.h = __float2bfloat16(f);
    return c.u;
}
__device__ __forceinline__ float bf2f(u16 u) {
    return __uint_as_float(((unsigned)u) << 16);
}
__device__ __forceinline__ unsigned cvtpk2(float lo, float hi) {
    unsigned r;
    asm("v_cvt_pk_bf16_f32 %0, %1, %2" : "=v"(r) : "v"(lo), "v"(hi));
    return r;
}
// raw v_exp_f32 (2^x), no OCML range fixup
__device__ __forceinline__ float fast_exp2(float x) {
    float r;
    asm("v_exp_f32 %0, %1" : "=v"(r) : "v"(x));
    return r;
}
// async global->LDS, 16B per lane; lds dest is wave-uniform base + lane*16
__device__ __forceinline__ void gload16(const void* g, void* l) {
    __builtin_amdgcn_global_load_lds((const __attribute__((address_space(1))) void*)g,
                                     (__attribute__((address_space(3))) void*)l, 16, 0, 0);
}

// ---------------- fused: pre (pos conv + LN1 + region softmax) / weight convert / kt pad-zero ----------------
__global__ __launch_bounds__(256) void fused_pre_kernel(
    const float* __restrict__ x, const float* __restrict__ queries, const int* __restrict__ epoch,
    const float* __restrict__ pos_w, const float* __restrict__ pos_b,
    const float* __restrict__ ln_g, const float* __restrict__ ln_b,
    const float* __restrict__ qw, const float* __restrict__ kw, const float* __restrict__ vw,
    const float* __restrict__ ow, const float* __restrict__ f1, const float* __restrict__ f2,
    float* __restrict__ xq, u16* __restrict__ ybf, u16* __restrict__ pbf,
    u16* __restrict__ wbf, u16* __restrict__ kt)
{
    int bi = blockIdx.x;
    if (bi >= 9248) {
        int bj = bi - 9248;
        if (bj < 768) {
            int i4 = bj * 256 + threadIdx.x;
            int idx = i4 * 4;
            const float* src; int off;
            if      (idx < 65536)  { src = qw; off = idx; }
            else if (idx < 131072) { src = kw; off = idx - 65536; }
            else if (idx < 196608) { src = vw; off = idx - 131072; }
            else if (idx < 262144) { src = ow; off = idx - 196608; }
            else if (idx < 524288) { src = f1; off = idx - 262144; }
            else                   { src = f2; off = idx - 524288; }
            float4 v = *(const float4*)(src + off);
            ushort4 o;
            o.x = f2bf(v.x); o.y = f2bf(v.y); o.z = f2bf(v.z); o.w = f2bf(v.w);
            *(ushort4*)(wbf + idx) = o;
        } else {
            int idx = (bj - 768) * 256 + threadIdx.x;  // 1024 rows * 56 pad cols
            if (idx < 1024 * 56) {
                int row = idx / 56, col = idx - row * 56;
                kt[(size_t)row * KTLDc + 2312 + col] = 0;
            }
        }
        return;
    }
    int blk = bi;                        // 0..9247
    int b = blk / Nc, n = blk - b * Nc;
    int c = threadIdx.x;
    bool sp = (n >= NQc);
    float val;
    if (sp) {
        int s = n - NQc;
        int hh = s / Wc, ww = s - hh * Wc;
        float acc = pos_b[c];
        float center = x[((b * Hc + hh) * Wc + ww) * Cc + c];
#pragma unroll
        for (int kh = 0; kh < 3; ++kh) {
            int yy = hh + kh - 1;
            if (yy < 0 || yy >= Hc) continue;
#pragma unroll
            for (int kw2 = 0; kw2 < 3; ++kw2) {
                int xx = ww + kw2 - 1;
                if (xx < 0 || xx >= Wc) continue;
                acc += x[((b * Hc + yy) * Wc + xx) * Cc + c] * pos_w[(kh * 3 + kw2) * Cc + c];
            }
        }
        val = center + acc;
    } else {
        val = queries[(b * NQc + n) * Cc + c];
    }
    xq[(size_t)blk * Cc + c] = val;

    float pq[8];
#pragma unroll
    for (int qi = 0; qi < 8; ++qi)
        pq[qi] = sp ? val * queries[(b * NQc + qi) * Cc + c] : 0.f;
    float r0 = val, r1 = val * val;
#pragma unroll
    for (int off = 32; off; off >>= 1) {
        r0 += __shfl_xor(r0, off);
        r1 += __shfl_xor(r1, off);
#pragma unroll
        for (int qi = 0; qi < 8; ++qi) pq[qi] += __shfl_xor(pq[qi], off);
    }
    __shared__ float red[4][10];
    __shared__ float fin[10];
    int wv = c >> 6, ln = c & 63;
    if (ln == 0) {
        red[wv][0] = r0; red[wv][1] = r1;
#pragma unroll
        for (int qi = 0; qi < 8; ++qi) red[wv][2 + qi] = pq[qi];
    }
    __syncthreads();
    if (c < 10) fin[c] = red[0][c] + red[1][c] + red[2][c] + red[3][c];
    __syncthreads();
    float mean = fin[0] * (1.0f / 256.0f);
    float var  = fin[1] * (1.0f / 256.0f) - mean * mean;
    float inv  = rsqrtf(var + 1e-6f);
    ybf[(size_t)blk * Cc + c] = f2bf((val - mean) * inv * ln_g[c] + ln_b[c]);

    if (sp && c < 8) {
        float it = 1.0f / (2.0f * powf(0.05f, (float)(*epoch) / 200.0f));
        float mx = -1e30f;
        float lg[8];
#pragma unroll
        for (int qi = 0; qi < 8; ++qi) { lg[qi] = fin[2 + qi] * it; mx = fmaxf(mx, lg[qi]); }
        float s = 0.f, mine = 0.f;
#pragma unroll
        for (int qi = 0; qi < 8; ++qi) {
            float ev = __expf(lg[qi] - mx);
            s += ev;
            if (qi == c) mine = ev;
        }
        pbf[((size_t)b * HWc + (n - NQc)) * 8 + c] = f2bf(mine / s);
    }
}

// ---------------- 64x128-tile GEMM (high block-count variant) ----------------
// OMODE: 0=f32 out, 1=bf16 out, 3=f32 out permuted to d_out layout (N==256)
template <int ACT, int RESID, int OMODE>
__global__ __launch_bounds__(256) void mfma_gemm64_kernel(
    const u16* __restrict__ A, const u16* __restrict__ W,
    const float* __restrict__ bias, const float* resid,
    float* outF, u16* outB, int M, int N, int K, float scale)
{
    __shared__ u16 As[64 * 64];
    __shared__ u16 Bs[128 * 64];
    int t = threadIdx.x;
    int w = t >> 6, l = t & 63, lg = l >> 4, lr = l & 15;
    int wm = w >> 1, wn = w & 1;
    int m0 = blockIdx.y * 64, n0 = blockIdx.x * 128;
    f32x4 acc[2][4] = {};
    int lrow = l >> 3, lchunk = (l & 7) * 8;
    for (int k0 = 0; k0 < K; k0 += 64) {
        __syncthreads();
#pragma unroll
        for (int c = 0; c < 2; ++c) {
            int ar = m0 + w * 16 + c * 8 + lrow;
            if (ar >= M) ar = M - 1;
            gload16(A + (size_t)ar * K + k0 + lchunk, As + (w * 16 + c * 8) * 64);
        }
#pragma unroll
        for (int c = 0; c < 4; ++c) {
            int br = n0 + w * 32 + c * 8 + lrow;
            gload16(W + (size_t)br * K + k0 + lchunk, Bs + (w * 32 + c * 8) * 64);
        }
        __syncthreads();
#pragma unroll
        for (int kk = 0; kk < 64; kk += 32) {
            s8v aF[2], bF[4];
#pragma unroll
            for (int i = 0; i < 2; ++i)
                aF[i] = *(s8v*)&As[(wm * 32 + i * 16 + lr) * 64 + kk + lg * 8];
#pragma unroll
            for (int j = 0; j < 4; ++j)
                bF[j] = *(s8v*)&Bs[(wn * 64 + j * 16 + lr) * 64 + kk + lg * 8];
#pragma unroll
            for (int i = 0; i < 2; ++i)
#pragma unroll
                for (int j = 0; j < 4; ++j)
                    acc[i][j] = __builtin_amdgcn_mfma_f32_16x16x32_bf16(aF[i], bF[j], acc[i][j], 0, 0, 0);
        }
    }
#pragma unroll
    for (int j = 0; j < 4; ++j) {
        int n = n0 + wn * 64 + j * 16 + lr;
        float bv = bias[n];
#pragma unroll
        for (int i = 0; i < 2; ++i) {
#pragma unroll
            for (int r = 0; r < 4; ++r) {
                int m = m0 + wm * 32 + i * 16 + lg * 4 + r;
                if (m >= M) continue;
                float v = (acc[i][j][r] + bv) * scale;
                if (ACT == 1) {
                    float e = fast_exp2(2.302118f * (v + 0.044715f * v * v * v));
                    v = v * e * __builtin_amdgcn_rcpf(e + 1.0f);
                }
                if (RESID) v += resid[(size_t)m * N + n];
                if (OMODE == 0) {
                    outF[(size_t)m * N + n] = v;
                } else if (OMODE == 3) {
                    unsigned bb2 = (unsigned)m / 2312u;
                    unsigned tok = (unsigned)m - bb2 * 2312u;
                    size_t ob = (tok >= 8) ? (((size_t)(bb2 * 2304 + tok - 8)) << 8)
                                           : ((size_t)2359296 + (((size_t)(bb2 * 8 + tok)) << 8));
                    outF[ob + n] = v;
                } else {
                    outB[(size_t)m * N + n] = f2bf(v);
                }
            }
        }
    }
}

// ---------------- fused out-proj(+lepe A-sum) + residual + LN2: 32x256 tile, 289 blocks ----------------
// A = obf + lepebf (spatial rows), reg-staged once into padded LDS; out = A @ w_o^T + out_b + xq; ybf = LN(out)
__global__ __launch_bounds__(256) void mfma_gemm_oln_kernel(
    const u16* __restrict__ A, const u16* __restrict__ L,
    const u16* __restrict__ W, const float* __restrict__ bias,
    float* __restrict__ xq, const float* __restrict__ g, const float* __restrict__ bb,
    u16* __restrict__ ybf)
{
    const int K = Cc;
    constexpr int ALD = 264;        // padded A row stride (u16): 528 B -> 2-way banks on stride-16 reads
    __shared__ u16 As[32 * ALD];    // 16.5 KB, full-K A tile staged once
    __shared__ u16 Bs[256 * 64];    // 32 KB
    __shared__ float R[32][4][2];
    __shared__ float MI[32][2];
    int t = threadIdx.x;
    int w = t >> 6, l = t & 63, lg = l >> 4, lr = l & 15;
    int m0 = blockIdx.x * 32;
    int lrow = l >> 3, lchunk = (l & 7) * 8;

    // stage A = obf + lepe (coalesced pair-load + add, 4 units/thread)
    for (int u = t; u < 1024; u += 256) {
        int row = u >> 5;
        int cg  = (u & 31) * 8;
        int m = m0 + row;
        int b2 = m / 2312, n = m - b2 * 2312;
        union { s8v s; u16 us[8]; } ov, res;
        ov.s = *(const s8v*)&A[(size_t)m * Cc + cg];
        if (n >= NQc) {
            union { s8v s; u16 us[8]; } lv;
            lv.s = *(const s8v*)&L[((size_t)b2 * HWc + (n - NQc)) * Cc + cg];
#pragma unroll
            for (int i = 0; i < 8; ++i) res.us[i] = f2bf(bf2f(ov.us[i]) + bf2f(lv.us[i]));
        } else {
            res.s = ov.s;
        }
        *(s8v*)&As[row * ALD + cg] = res.s;
    }

    f32x4 acc[2][4] = {};
    for (int k0 = 0; k0 < K; k0 += 64) {
        __syncthreads();   // first iteration also covers As ds_writes
#pragma unroll
        for (int c = 0; c < 8; ++c)
            gload16(W + (size_t)(w * 64 + c * 8 + lrow) * K + k0 + lchunk, Bs + (w * 64 + c * 8) * 64);
        __syncthreads();
#pragma unroll
        for (int kk = 0; kk < 64; kk += 32) {
            s8v aF[2], bF[4];
#pragma unroll
            for (int i = 0; i < 2; ++i)
                aF[i] = *(s8v*)&As[(i * 16 + lr) * ALD + k0 + kk + lg * 8];
#pragma unroll
            for (int j = 0; j < 4; ++j)
                bF[j] = *(s8v*)&Bs[(w * 64 + j * 16 + lr) * 64 + kk + lg * 8];
#pragma unroll
            for (int i = 0; i < 2; ++i)
#pragma unroll
                for (int j = 0; j < 4; ++j)
                    acc[i][j] = __builtin_amdgcn_mfma_f32_16x16x32_bf16(aF[i], bF[j], acc[i][j], 0, 0, 0);
        }
    }
    float s[2][4], ss[2][4];
#pragma unroll
    for (int i = 0; i < 2; ++i)
#pragma unroll
        for (int r = 0; r < 4; ++r) { s[i][r] = 0.f; ss[i][r] = 0.f; }
#pragma unroll
    for (int j = 0; j < 4; ++j) {
        int n = w * 64 + j * 16 + lr;
        float bv = bias[n];
#pragma unroll
        for (int i = 0; i < 2; ++i) {
#pragma unroll
            for (int r = 0; r < 4; ++r) {
                int m = m0 + i * 16 + lg * 4 + r;
                float v = acc[i][j][r] + bv + xq[(size_t)m * Cc + n];
                acc[i][j][r] = v;
                xq[(size_t)m * Cc + n] = v;
                s[i][r] += v;
                ss[i][r] += v * v;
            }
        }
    }
#pragma unroll
    for (int i = 0; i < 2; ++i)
#pragma unroll
        for (int r = 0; r < 4; ++r) {
#pragma unroll
            for (int off = 1; off < 16; off <<= 1) {
                s[i][r]  += __shfl_xor(s[i][r], off);
                ss[i][r] += __shfl_xor(ss[i][r], off);
            }
        }
    __syncthreads();
    if (lr == 0) {
#pragma unroll
        for (int i = 0; i < 2; ++i)
#pragma unroll
            for (int r = 0; r < 4; ++r) {
                int row = i * 16 + lg * 4 + r;
                R[row][w][0] = s[i][r];
                R[row][w][1] = ss[i][r];
            }
    }
    __syncthreads();
    if (t < 32) {
        float tot  = R[t][0][0] + R[t][1][0] + R[t][2][0] + R[t][3][0];
        float tots = R[t][0][1] + R[t][1][1] + R[t][2][1] + R[t][3][1];
        float mean = tot * (1.0f / 256.0f);
        float var  = tots * (1.0f / 256.0f) - mean * mean;
        MI[t][0] = mean;
        MI[t][1] = rsqrtf(var + 1e-6f);
    }
    __syncthreads();
#pragma unroll
    for (int j = 0; j < 4; ++j) {
        int n = w * 64 + j * 16 + lr;
        float gv = g[n], bbv = bb[n];
#pragma unroll
        for (int i = 0; i < 2; ++i) {
#pragma unroll
            for (int r = 0; r < 4; ++r) {
                int row = i * 16 + lg * 4 + r;
                float mean = MI[row][0], inv = MI[row][1];
                int m = m0 + row;
                ybf[(size_t)m * Cc + n] = f2bf((acc[i][j][r] - mean) * inv * gv + bbv);
            }
        }
    }
}

// ---------------- fused QKV GEMM, 64x128 tile (870 blocks), N=768, K=256 ----------------
__global__ __launch_bounds__(256) void mfma_gemm_qkv64_kernel(
    const u16* __restrict__ A, const u16* __restrict__ W,
    const float* __restrict__ q_b, const float* __restrict__ k_b, const float* __restrict__ v_b,
    u16* __restrict__ outq, u16* __restrict__ outk, u16* __restrict__ outkt, u16* __restrict__ outv)
{
    const int M = MRc, K = Cc;
    __shared__ u16 As[64 * 64];
    __shared__ u16 Bs[128 * 64];
    int t = threadIdx.x;
    int w = t >> 6, l = t & 63, lg = l >> 4, lr = l & 15;
    int wm = w >> 1, wn = w & 1;
    int m0 = blockIdx.y * 64, n0 = blockIdx.x * 128;
    int range = n0 >> 8;  // n0 in {0,128,256,384,512,640} -> 0,0,1,1,2,2
    f32x4 acc[2][4] = {};
    int lrow = l >> 3, lchunk = (l & 7) * 8;
    for (int k0 = 0; k0 < K; k0 += 64) {
        __syncthreads();
#pragma unroll
        for (int c = 0; c < 2; ++c) {
            int ar = m0 + w * 16 + c * 8 + lrow;
            if (ar >= M) ar = M - 1;
            gload16(A + (size_t)ar * K + k0 + lchunk, As + (w * 16 + c * 8) * 64);
        }
#pragma unroll
        for (int c = 0; c < 4; ++c) {
            int br = n0 + w * 32 + c * 8 + lrow;
            gload16(W + (size_t)br * K + k0 + lchunk, Bs + (w * 32 + c * 8) * 64);
        }
        __syncthreads();
#pragma unroll
        for (int kk = 0; kk < 64; kk += 32) {
            s8v aF[2], bF[4];
#pragma unroll
            for (int i = 0; i < 2; ++i)
                aF[i] = *(s8v*)&As[(wm * 32 + i * 16 + lr) * 64 + kk + lg * 8];
#pragma unroll
            for (int j = 0; j < 4; ++j)
                bF[j] = *(s8v*)&Bs[(wn * 64 + j * 16 + lr) * 64 + kk + lg * 8];
#pragma unroll
            for (int i = 0; i < 2; ++i)
#pragma unroll
                for (int j = 0; j < 4; ++j)
                    acc[i][j] = __builtin_amdgcn_mfma_f32_16x16x32_bf16(aF[i], bF[j], acc[i][j], 0, 0, 0);
        }
    }
    const float* bias = (range == 0) ? q_b : (range == 1) ? k_b : v_b;
    u16* dst = (range == 0) ? outq : (range == 1) ? outk : outv;
    float scale = (range == 0) ? LOG2Ec : (range == 1) ? KSCALEc : 1.0f;
#pragma unroll
    for (int j = 0; j < 4; ++j) {
        int n = n0 + wn * 64 + j * 16 + lr;
        int nc = n & 255;
        float bv = bias[nc];
#pragma unroll
        for (int i = 0; i < 2; ++i) {
#pragma unroll
            for (int r = 0; r < 4; ++r) {
                int m = m0 + wm * 32 + i * 16 + lg * 4 + r;
                if (m >= M) continue;
                float v = (acc[i][j][r] + bv) * scale;
                u16 hv = f2bf(v);
                dst[(size_t)m * 256 + nc] = hv;
                if (range == 1) {
                    unsigned um = (unsigned)m;
                    unsigned bb = um / 2312u;
                    unsigned nr = um - bb * 2312u;
                    outkt[((size_t)(bb * NHc + (nc >> 5)) * Dc + (nc & 31)) * KTLDc + nr] = hv;
                }
            }
        }
    }
}

// ---------------- MFMA flash attention + co-launched lepe conv (blocks >= 1184) ----------------
// attn path (blocks 0..1183) byte-identical to the proven round-16 structure.
// lepe path (blocks 1184..2335): dwconv5x5(vbf) -> lepebf standalone (no obf dependency).
__global__ __launch_bounds__(256, 4) void attn_mfma_kernel(const u16* __restrict__ q,
                                                           const u16* __restrict__ k,
                                                           const u16* __restrict__ kt,
                                                           const u16* __restrict__ p,
                                                           u16* __restrict__ o,
                                                           const u16* __restrict__ v,
                                                           const float* __restrict__ lw,
                                                           const float* __restrict__ lbias,
                                                           u16* __restrict__ lepebf)
{
    constexpr int KT = 64;
    constexpr int NT = (Nc + KT - 1) / KT;  // 37
    __shared__ __align__(16) u16 Kls[KT * 40];     // [kv][d]
    __shared__ __align__(16) u16 Ktls[32 * 88];    // [d][kv]
    __shared__ __align__(16) unsigned PW[4][16 * 36]; // per-wave packed P

    int flat = blockIdx.x;
    if (flat >= 1184) {
        // ---- lepe path: fills idle occupancy while attn blocks run ----
        int idx = (flat - 1184) * 256 + threadIdx.x;   // 294912 units
        int cg = (idx & 31) * 8;
        int sp = idx >> 5;
        int ww = sp % Wc;
        int t2 = sp / Wc;
        int hh = t2 % Hc;
        int b  = t2 / Hc;
        float acc[8];
#pragma unroll
        for (int i = 0; i < 8; ++i) acc[i] = lbias[cg + i];
#pragma unroll
        for (int kh = 0; kh < 5; ++kh) {
            int yy = hh + kh - 2;
            if (yy < 0 || yy >= Hc) continue;
#pragma unroll
            for (int kw = 0; kw < 5; ++kw) {
                int xx = ww + kw - 2;
                if (xx < 0 || xx >= Wc) continue;
                union { s8v s; u16 u[8]; } uv;
                uv.s = *(const s8v*)&v[((size_t)b * Nc + NQc + yy * Wc + xx) * Cc + cg];
                const float4* wp = (const float4*)&lw[(kh * 5 + kw) * Cc + cg];
                float4 w0 = wp[0], w1 = wp[1];
                acc[0] += bf2f(uv.u[0]) * w0.x;
                acc[1] += bf2f(uv.u[1]) * w0.y;
                acc[2] += bf2f(uv.u[2]) * w0.z;
                acc[3] += bf2f(uv.u[3]) * w0.w;
                acc[4] += bf2f(uv.u[4]) * w1.x;
                acc[5] += bf2f(uv.u[5]) * w1.y;
                acc[6] += bf2f(uv.u[6]) * w1.z;
                acc[7] += bf2f(uv.u[7]) * w1.w;
            }
        }
        union { s8v s; u16 u[8]; } res;
#pragma unroll
        for (int i = 0; i < 8; ++i) res.u[i] = f2bf(acc[i]);
        *(s8v*)&lepebf[((size_t)t2 * Wc + ww) * Cc + cg] = res.s;
        return;
    }

    int grp  = flat & 31;       // (b,h) group -> XCD-local
    int qblk = flat >> 5;       // 0..36
    int b = grp >> 3, h = grp & 7;

    int t = threadIdx.x;
    int w = t >> 6, l = t & 63, lg = l >> 4, lr = l & 15;
    int q0 = qblk * 64 + w * 16;

    int qrow = q0 + lr;
    bool qtok = (qrow < NQc);
    int qrc = qrow < Nc ? qrow : Nc - 1;
    s8v qB = *(const s8v*)&q[((size_t)b * Nc + qrc) * Cc + h * Dc + lg * 8];

    s8v pqB = {0, 0, 0, 0, 0, 0, 0, 0};
    if (lg == 0 && qrow >= NQc && qrow < Nc)
        pqB = *(const s8v*)&p[((size_t)b * HWc + (qrow - NQc)) * 8];

    f32x4 accO[2] = {{0.f, 0.f, 0.f, 0.f}, {0.f, 0.f, 0.f, 0.f}};
    float lrun = 0.f;

    int srow = t >> 2, sseg = (t & 3) * 8;     // K staging
    int td = t >> 3, tks = (t & 7) * 8;        // Kt staging
    const u16* ktbase = kt + ((size_t)(b * NHc + h) * Dc + td) * KTLDc;
    const u16* pbase  = p + (size_t)b * HWc * 8;
    unsigned* PWr = &PW[w][lr * 36];
    int bsrc = lg * 20;  // broadcast source lane base

    s8v kv8 = {0,0,0,0,0,0,0,0};
    if (srow < Nc)
        kv8 = *(const s8v*)&k[((size_t)b * Nc + srow) * Cc + h * Dc + sseg];
    s8v kt8 = *(const s8v*)&ktbase[tks];

    for (int ti = 0; ti < NT; ++ti) {
        int m0 = ti * KT;
        bool tail = (ti == NT - 1);
        __syncthreads();
        *(s8v*)&Kls[srow * 40 + sseg] = kv8;
        *(s8v*)&Ktls[td * 88 + tks]   = kt8;
        __syncthreads();

        if (ti + 1 < NT) {
            int n0g = m0 + KT;
            kv8 = (s8v){0,0,0,0,0,0,0,0};
            int kvg = n0g + srow;
            if (kvg < Nc)
                kv8 = *(const s8v*)&k[((size_t)b * Nc + kvg) * Cc + h * Dc + sseg];
            kt8 = *(const s8v*)&ktbase[n0g + tks];
        }

        float sc[4][4];
#pragma unroll
        for (int cb = 0; cb < 4; ++cb) {
            s8v kA = *(s8v*)&Kls[(cb * 16 + lr) * 40 + lg * 8];
            f32x4 St = __builtin_amdgcn_mfma_f32_16x16x32_bf16(kA, qB, (f32x4){0.f,0.f,0.f,0.f}, 0, 0, 0);
            s8v pkA = {0, 0, 0, 0, 0, 0, 0, 0};
            if (lg == 0) {
                int kvr = m0 + cb * 16 + lr;
                if (kvr >= NQc && kvr < Nc)
                    pkA = *(const s8v*)&pbase[(size_t)(kvr - NQc) * 8];
            }
            f32x4 Mv = __builtin_amdgcn_mfma_f32_16x16x32_bf16(pkA, pqB, (f32x4){0.f,0.f,0.f,0.f}, 0, 0, 0);
            bool ktok = (ti == 0 && cb == 0 && lg < 2);  // kv-row < 8
#pragma unroll
            for (int j = 0; j < 4; ++j) {
                float mval = (qtok || ktok) ? 1.f : Mv[j];
                sc[cb][j] = St[j] * mval;
            }
        }
        // softmax numerator: q pre-scaled by log2e -> raw v_exp_f32 (fixed shift 0, |S|<=~2)
        float tsum = 0.f;
#pragma unroll
        for (int cb = 0; cb < 4; ++cb)
#pragma unroll
            for (int j = 0; j < 4; ++j) {
                float ev = fast_exp2(sc[cb][j]);
                if (tail && (cb != 0 || lg >= 2)) ev = 0.f;  // kv >= Nc
                sc[cb][j] = ev;
                tsum += ev;
            }
        tsum += __shfl_xor(tsum, 16);
        tsum += __shfl_xor(tsum, 32);
        lrun += tsum;
#pragma unroll
        for (int cb = 0; cb < 4; ++cb) {
            uint2 pk2;
            pk2.x = cvtpk2(sc[cb][0], sc[cb][1]);
            pk2.y = cvtpk2(sc[cb][2], sc[cb][3]);
            *(uint2*)&PWr[8 * cb + 2 * lg] = pk2;
        }
#pragma unroll
        for (int kc = 0; kc < 2; ++kc) {
            s8v pA = *(s8v*)&PWr[16 * kc + 4 * lg];
#pragma unroll
            for (int db = 0; db < 2; ++db) {
                s8v vB = *(s8v*)&Ktls[(db * 16 + lr) * 88 + kc * 32 + lg * 8];
                accO[db] = __builtin_amdgcn_mfma_f32_16x16x32_bf16(pA, vB, accO[db], 0, 0, 0);
            }
        }
    }

    float lb[4];
#pragma unroll
    for (int j = 0; j < 4; ++j) lb[j] = __shfl(lrun, bsrc + j);
#pragma unroll
    for (int db = 0; db < 2; ++db)
#pragma unroll
        for (int j = 0; j < 4; ++j) {
            int rowg = q0 + lg * 4 + j;
            if (rowg < Nc)
                o[((size_t)b * Nc + rowg) * Cc + h * Dc + db * 16 + lr] = f2bf(accO[db][j] / lb[j]);
        }
}

extern "C" void kernel_launch(void* const* d_in, const int* in_sizes, int n_in,
                              void* d_out, int out_size, void* d_ws, size_t ws_size,
                              hipStream_t stream)
{
    const float* x       = (const float*)d_in[0];
    const float* queries = (const float*)d_in[1];
    const int*   epoch   = (const int*)d_in[2];
    const float* pos_w   = (const float*)d_in[3];
    const float* pos_b   = (const float*)d_in[4];
    const float* ln1_g   = (const float*)d_in[5];
    const float* ln1_b   = (const float*)d_in[6];
    const float* q_w     = (const float*)d_in[7];
    const float* q_b     = (const float*)d_in[8];
    const float* k_w     = (const float*)d_in[9];
    const float* k_b     = (const float*)d_in[10];
    const float* v_w     = (const float*)d_in[11];
    const float* v_b     = (const float*)d_in[12];
    const float* lepe_w  = (const float*)d_in[13];
    const float* lepe_b  = (const float*)d_in[14];
    const float* out_w   = (const float*)d_in[15];
    const float* out_b   = (const float*)d_in[16];
    const float* ln2_g   = (const float*)d_in[17];
    const float* ln2_b   = (const float*)d_in[18];
    const float* fc1_w   = (const float*)d_in[19];
    const float* fc1_b   = (const float*)d_in[20];
    const float* fc2_w   = (const float*)d_in[21];
    const float* fc2_b   = (const float*)d_in[22];

    float* ws = (float*)d_ws;
    float* xq  = ws;                        // f32, 2,367,488
    u16*  ybf  = (u16*)(ws + 2367488);      // bf16 2,367,488 (1,183,744 slots)
    u16*  qbf  = (u16*)(ws + 3551232);      // bf16 2,367,488
    u16*  kbf  = (u16*)(ws + 4734976);      // bf16 2,367,488
    u16*  ktbf = (u16*)(ws + 5918720);      // bf16 4*8*32*2368 = 2,424,832 (1,212,416 slots)
    u16*  pbf  = (u16*)(ws + 7131136);      // bf16 73,728 (36,864 slots)
    u16*  obf  = (u16*)(ws + 7168000);      // bf16 2,367,488
    u16*  vbf  = (u16*)(ws + 8351744);      // bf16 2,367,488
    u16*  wbf  = (u16*)(ws + 9535488);      // bf16 786,432 (weights; 393,216 slots)
    u16*  lepebf = (u16*)(ws + 9928704);    // bf16 2,359,296 (lepe conv result)
    u16*  ffn  = qbf;                       // fc1 act aliases qbf..obf (dead by then)

    u16* w_o  = wbf + 196608;
    u16* w_f1 = wbf + 262144;
    u16* w_f2 = wbf + 524288;

    fused_pre_kernel<<<9248 + 768 + 224, 256, 0, stream>>>(
        x, queries, epoch, pos_w, pos_b, ln1_g, ln1_b,
        q_w, k_w, v_w, out_w, fc1_w, fc2_w,
        xq, ybf, pbf, wbf, ktbf);

    mfma_gemm_qkv64_kernel<<<dim3(6, 145), 256, 0, stream>>>(ybf, wbf, q_b, k_b, v_b, qbf, kbf, ktbf, vbf);

    // attn (1184 blocks) + co-launched lepe conv (1152 blocks) fill idle occupancy
    attn_mfma_kernel<<<1184 + 1152, 256, 0, stream>>>(qbf, kbf, ktbf, pbf, obf,
                                                      vbf, lepe_w, lepe_b, lepebf);

    mfma_gemm_oln_kernel<<<289, 256, 0, stream>>>(obf, lepebf, w_o, out_b, xq, ln2_g, ln2_b, ybf);

    mfma_gemm64_kernel<1,0,1><<<dim3(8, 145), 256, 0, stream>>>(ybf, w_f1, fc1_b, nullptr, nullptr, ffn, MRc, 1024, 256, 1.0f);
    mfma_gemm64_kernel<0,1,3><<<dim3(2, 145), 256, 0, stream>>>(ffn, w_f2, fc2_b, xq, (float*)d_out, nullptr, MRc, 256, 1024, 1.0f);
}

// Round 23
// 190.189 us; speedup vs baseline: 1.1832x; 1.0237x over previous
//
#include <hip/hip_runtime.h>
#include <hip/hip_bf16.h>
#include <math.h>

typedef unsigned short u16;
constexpr int Bc = 4, Hc = 48, Wc = 48, Cc = 256;
constexpr int NQc = 8, HWc = 2304, Nc = 2312, NHc = 8, Dc = 32, FFNc = 1024;
constexpr int MRc = Bc * Nc; // 9248
constexpr int KTLDc = 2368;  // padded kv length for transposed K (37*64)
constexpr float KSCALEc = 0.17677669529663687f; // (256/8)^-0.5
constexpr float LOG2Ec  = 1.4426950408889634f;

typedef __attribute__((ext_vector_type(8))) short s8v;
typedef __attribute__((ext_vector_type(4))) float f32x4;

__device__ __forceinline__ u16 f2bf(float f) {
    union { __hip_bfloat16 h; u16 u; } c;
    c.h = __float2bfloat16(f);
    return c.u;
}
__device__ __forceinline__ float bf2f(u16 u) {
    return __uint_as_float(((unsigned)u) << 16);
}
__device__ __forceinline__ unsigned cvtpk2(float lo, float hi) {
    unsigned r;
    asm("v_cvt_pk_bf16_f32 %0, %1, %2" : "=v"(r) : "v"(lo), "v"(hi));
    return r;
}
// raw v_exp_f32 (2^x), no OCML range fixup
__device__ __forceinline__ float fast_exp2(float x) {
    float r;
    asm("v_exp_f32 %0, %1" : "=v"(r) : "v"(x));
    return r;
}
// async global->LDS, 16B per lane; lds dest is wave-uniform base + lane*16
__device__ __forceinline__ void gload16(const void* g, void* l) {
    __builtin_amdgcn_global_load_lds((const __attribute__((address_space(1))) void*)g,
                                     (__attribute__((address_space(3))) void*)l, 16, 0, 0);
}

// ---------------- fused: pre (pos conv + LN1 + region softmax) / weight convert / kt pad-zero ----------------
__global__ __launch_bounds__(256) void fused_pre_kernel(
    const float* __restrict__ x, const float* __restrict__ queries, const int* __restrict__ epoch,
    const float* __restrict__ pos_w, const float* __restrict__ pos_b,
    const float* __restrict__ ln_g, const float* __restrict__ ln_b,
    const float* __restrict__ qw, const float* __restrict__ kw, const float* __restrict__ vw,
    const float* __restrict__ ow, const float* __restrict__ f1, const float* __restrict__ f2,
    float* __restrict__ xq, u16* __restrict__ ybf, u16* __restrict__ pbf,
    u16* __restrict__ wbf, u16* __restrict__ kt)
{
    int bi = blockIdx.x;
    if (bi >= 9248) {
        int bj = bi - 9248;
        if (bj < 768) {
            int i4 = bj * 256 + threadIdx.x;
            int idx = i4 * 4;
            const float* src; int off;
            if      (idx < 65536)  { src = qw; off = idx; }
            else if (idx < 131072) { src = kw; off = idx - 65536; }
            else if (idx < 196608) { src = vw; off = idx - 131072; }
            else if (idx < 262144) { src = ow; off = idx - 196608; }
            else if (idx < 524288) { src = f1; off = idx - 262144; }
            else                   { src = f2; off = idx - 524288; }
            float4 v = *(const float4*)(src + off);
            ushort4 o;
            o.x = f2bf(v.x); o.y = f2bf(v.y); o.z = f2bf(v.z); o.w = f2bf(v.w);
            *(ushort4*)(wbf + idx) = o;
        } else {
            int idx = (bj - 768) * 256 + threadIdx.x;  // 1024 rows * 56 pad cols
            if (idx < 1024 * 56) {
                int row = idx / 56, col = idx - row * 56;
                kt[(size_t)row * KTLDc + 2312 + col] = 0;
            }
        }
        return;
    }
    int blk = bi;                        // 0..9247
    int b = blk / Nc, n = blk - b * Nc;
    int c = threadIdx.x;
    bool sp = (n >= NQc);
    float val;
    if (sp) {
        int s = n - NQc;
        int hh = s / Wc, ww = s - hh * Wc;
        float acc = pos_b[c];
        float center = x[((b * Hc + hh) * Wc + ww) * Cc + c];
#pragma unroll
        for (int kh = 0; kh < 3; ++kh) {
            int yy = hh + kh - 1;
            if (yy < 0 || yy >= Hc) continue;
#pragma unroll
            for (int kw2 = 0; kw2 < 3; ++kw2) {
                int xx = ww + kw2 - 1;
                if (xx < 0 || xx >= Wc) continue;
                acc += x[((b * Hc + yy) * Wc + xx) * Cc + c] * pos_w[(kh * 3 + kw2) * Cc + c];
            }
        }
        val = center + acc;
    } else {
        val = queries[(b * NQc + n) * Cc + c];
    }
    xq[(size_t)blk * Cc + c] = val;

    float pq[8];
#pragma unroll
    for (int qi = 0; qi < 8; ++qi)
        pq[qi] = sp ? val * queries[(b * NQc + qi) * Cc + c] : 0.f;
    float r0 = val, r1 = val * val;
#pragma unroll
    for (int off = 32; off; off >>= 1) {
        r0 += __shfl_xor(r0, off);
        r1 += __shfl_xor(r1, off);
#pragma unroll
        for (int qi = 0; qi < 8; ++qi) pq[qi] += __shfl_xor(pq[qi], off);
    }
    __shared__ float red[4][10];
    __shared__ float fin[10];
    int wv = c >> 6, ln = c & 63;
    if (ln == 0) {
        red[wv][0] = r0; red[wv][1] = r1;
#pragma unroll
        for (int qi = 0; qi < 8; ++qi) red[wv][2 + qi] = pq[qi];
    }
    __syncthreads();
    if (c < 10) fin[c] = red[0][c] + red[1][c] + red[2][c] + red[3][c];
    __syncthreads();
    float mean = fin[0] * (1.0f / 256.0f);
    float var  = fin[1] * (1.0f / 256.0f) - mean * mean;
    float inv  = rsqrtf(var + 1e-6f);
    ybf[(size_t)blk * Cc + c] = f2bf((val - mean) * inv * ln_g[c] + ln_b[c]);

    if (sp && c < 8) {
        float it = 1.0f / (2.0f * powf(0.05f, (float)(*epoch) / 200.0f));
        float mx = -1e30f;
        float lg[8];
#pragma unroll
        for (int qi = 0; qi < 8; ++qi) { lg[qi] = fin[2 + qi] * it; mx = fmaxf(mx, lg[qi]); }
        float s = 0.f, mine = 0.f;
#pragma unroll
        for (int qi = 0; qi < 8; ++qi) {
            float ev = __expf(lg[qi] - mx);
            s += ev;
            if (qi == c) mine = ev;
        }
        pbf[((size_t)b * HWc + (n - NQc)) * 8 + c] = f2bf(mine / s);
    }
}

// ---------------- 64x128-tile GEMM (high block-count variant) ----------------
// OMODE: 0=f32 out, 1=bf16 out, 3=f32 out permuted to d_out layout (N==256)
template <int ACT, int RESID, int OMODE>
__global__ __launch_bounds__(256) void mfma_gemm64_kernel(
    const u16* __restrict__ A, const u16* __restrict__ W,
    const float* __restrict__ bias, const float* resid,
    float* outF, u16* outB, int M, int N, int K, float scale)
{
    __shared__ u16 As[64 * 64];
    __shared__ u16 Bs[128 * 64];
    int t = threadIdx.x;
    int w = t >> 6, l = t & 63, lg = l >> 4, lr = l & 15;
    int wm = w >> 1, wn = w & 1;
    int m0 = blockIdx.y * 64, n0 = blockIdx.x * 128;
    f32x4 acc[2][4] = {};
    int lrow = l >> 3, lchunk = (l & 7) * 8;
    for (int k0 = 0; k0 < K; k0 += 64) {
        __syncthreads();
#pragma unroll
        for (int c = 0; c < 2; ++c) {
            int ar = m0 + w * 16 + c * 8 + lrow;
            if (ar >= M) ar = M - 1;
            gload16(A + (size_t)ar * K + k0 + lchunk, As + (w * 16 + c * 8) * 64);
        }
#pragma unroll
        for (int c = 0; c < 4; ++c) {
            int br = n0 + w * 32 + c * 8 + lrow;
            gload16(W + (size_t)br * K + k0 + lchunk, Bs + (w * 32 + c * 8) * 64);
        }
        __syncthreads();
#pragma unroll
        for (int kk = 0; kk < 64; kk += 32) {
            s8v aF[2], bF[4];
#pragma unroll
            for (int i = 0; i < 2; ++i)
                aF[i] = *(s8v*)&As[(wm * 32 + i * 16 + lr) * 64 + kk + lg * 8];
#pragma unroll
            for (int j = 0; j < 4; ++j)
                bF[j] = *(s8v*)&Bs[(wn * 64 + j * 16 + lr) * 64 + kk + lg * 8];
#pragma unroll
            for (int i = 0; i < 2; ++i)
#pragma unroll
                for (int j = 0; j < 4; ++j)
                    acc[i][j] = __builtin_amdgcn_mfma_f32_16x16x32_bf16(aF[i], bF[j], acc[i][j], 0, 0, 0);
        }
    }
#pragma unroll
    for (int j = 0; j < 4; ++j) {
        int n = n0 + wn * 64 + j * 16 + lr;
        float bv = bias[n];
#pragma unroll
        for (int i = 0; i < 2; ++i) {
#pragma unroll
            for (int r = 0; r < 4; ++r) {
                int m = m0 + wm * 32 + i * 16 + lg * 4 + r;
                if (m >= M) continue;
                float v = (acc[i][j][r] + bv) * scale;
                if (ACT == 1) {
                    float e = fast_exp2(2.302118f * (v + 0.044715f * v * v * v));
                    v = v * e * __builtin_amdgcn_rcpf(e + 1.0f);
                }
                if (RESID) v += resid[(size_t)m * N + n];
                if (OMODE == 0) {
                    outF[(size_t)m * N + n] = v;
                } else if (OMODE == 3) {
                    unsigned bb2 = (unsigned)m / 2312u;
                    unsigned tok = (unsigned)m - bb2 * 2312u;
                    size_t ob = (tok >= 8) ? (((size_t)(bb2 * 2304 + tok - 8)) << 8)
                                           : ((size_t)2359296 + (((size_t)(bb2 * 8 + tok)) << 8));
                    outF[ob + n] = v;
                } else {
                    outB[(size_t)m * N + n] = f2bf(v);
                }
            }
        }
    }
}

// ---------------- 32x128-tile GEMM (max block-count, for long-K small-N shapes like fc2) ----------------
template <int RESID, int OMODE>
__global__ __launch_bounds__(256) void mfma_gemm32_kernel(
    const u16* __restrict__ A, const u16* __restrict__ W,
    const float* __restrict__ bias, const float* resid,
    float* outF, int M, int N, int K, float scale)
{
    __shared__ u16 As[32 * 64];    // 4 KB
    __shared__ u16 Bs[128 * 64];   // 16 KB
    int t = threadIdx.x;
    int w = t >> 6, l = t & 63, lg = l >> 4, lr = l & 15;
    int wm = w >> 1, wn = w & 1;   // wave = 16 rows x 64 cols
    int m0 = blockIdx.y * 32, n0 = blockIdx.x * 128;
    f32x4 acc[4] = {};
    int lrow = l >> 3, lchunk = (l & 7) * 8;
    for (int k0 = 0; k0 < K; k0 += 64) {
        __syncthreads();
        {   // A: 32 rows, wave w stages rows w*8..w*8+7
            int ar = m0 + w * 8 + lrow;
            if (ar >= M) ar = M - 1;
            gload16(A + (size_t)ar * K + k0 + lchunk, As + (w * 8) * 64);
        }
#pragma unroll
        for (int c = 0; c < 4; ++c) {
            int br = n0 + w * 32 + c * 8 + lrow;
            gload16(W + (size_t)br * K + k0 + lchunk, Bs + (w * 32 + c * 8) * 64);
        }
        __syncthreads();
#pragma unroll
        for (int kk = 0; kk < 64; kk += 32) {
            s8v aF = *(s8v*)&As[(wm * 16 + lr) * 64 + kk + lg * 8];
#pragma unroll
            for (int j = 0; j < 4; ++j) {
                s8v bF = *(s8v*)&Bs[(wn * 64 + j * 16 + lr) * 64 + kk + lg * 8];
                acc[j] = __builtin_amdgcn_mfma_f32_16x16x32_bf16(aF, bF, acc[j], 0, 0, 0);
            }
        }
    }
#pragma unroll
    for (int j = 0; j < 4; ++j) {
        int n = n0 + wn * 64 + j * 16 + lr;
        float bv = bias[n];
#pragma unroll
        for (int r = 0; r < 4; ++r) {
            int m = m0 + wm * 16 + lg * 4 + r;
            if (m >= M) continue;
            float v = (acc[j][r] + bv) * scale;
            if (RESID) v += resid[(size_t)m * N + n];
            if (OMODE == 0) {
                outF[(size_t)m * N + n] = v;
            } else {
                unsigned bb2 = (unsigned)m / 2312u;
                unsigned tok = (unsigned)m - bb2 * 2312u;
                size_t ob = (tok >= 8) ? (((size_t)(bb2 * 2304 + tok - 8)) << 8)
                                       : ((size_t)2359296 + (((size_t)(bb2 * 8 + tok)) << 8));
                outF[ob + n] = v;
            }
        }
    }
}

// ---------------- fused out-proj(+lepe A-sum) + residual + LN2: 32x256 tile, 289 blocks ----------------
__global__ __launch_bounds__(256) void mfma_gemm_oln_kernel(
    const u16* __restrict__ A, const u16* __restrict__ L,
    const u16* __restrict__ W, const float* __restrict__ bias,
    float* __restrict__ xq, const float* __restrict__ g, const float* __restrict__ bb,
    u16* __restrict__ ybf)
{
    const int K = Cc;
    constexpr int ALD = 264;        // padded A row stride (u16): 528 B -> 2-way banks on stride-16 reads
    __shared__ u16 As[32 * ALD];    // 16.5 KB, full-K A tile staged once
    __shared__ u16 Bs[256 * 64];    // 32 KB
    __shared__ float R[32][4][2];
    __shared__ float MI[32][2];
    int t = threadIdx.x;
    int w = t >> 6, l = t & 63, lg = l >> 4, lr = l & 15;
    int m0 = blockIdx.x * 32;
    int lrow = l >> 3, lchunk = (l & 7) * 8;

    // stage A = obf + lepe (coalesced pair-load + add, 4 units/thread)
    for (int u = t; u < 1024; u += 256) {
        int row = u >> 5;
        int cg  = (u & 31) * 8;
        int m = m0 + row;
        int b2 = m / 2312, n = m - b2 * 2312;
        union { s8v s; u16 us[8]; } ov, res;
        ov.s = *(const s8v*)&A[(size_t)m * Cc + cg];
        if (n >= NQc) {
            union { s8v s; u16 us[8]; } lv;
            lv.s = *(const s8v*)&L[((size_t)b2 * HWc + (n - NQc)) * Cc + cg];
#pragma unroll
            for (int i = 0; i < 8; ++i) res.us[i] = f2bf(bf2f(ov.us[i]) + bf2f(lv.us[i]));
        } else {
            res.s = ov.s;
        }
        *(s8v*)&As[row * ALD + cg] = res.s;
    }

    f32x4 acc[2][4] = {};
    for (int k0 = 0; k0 < K; k0 += 64) {
        __syncthreads();   // first iteration also covers As ds_writes
#pragma unroll
        for (int c = 0; c < 8; ++c)
            gload16(W + (size_t)(w * 64 + c * 8 + lrow) * K + k0 + lchunk, Bs + (w * 64 + c * 8) * 64);
        __syncthreads();
#pragma unroll
        for (int kk = 0; kk < 64; kk += 32) {
            s8v aF[2], bF[4];
#pragma unroll
            for (int i = 0; i < 2; ++i)
                aF[i] = *(s8v*)&As[(i * 16 + lr) * ALD + k0 + kk + lg * 8];
#pragma unroll
            for (int j = 0; j < 4; ++j)
                bF[j] = *(s8v*)&Bs[(w * 64 + j * 16 + lr) * 64 + kk + lg * 8];
#pragma unroll
            for (int i = 0; i < 2; ++i)
#pragma unroll
                for (int j = 0; j < 4; ++j)
                    acc[i][j] = __builtin_amdgcn_mfma_f32_16x16x32_bf16(aF[i], bF[j], acc[i][j], 0, 0, 0);
        }
    }
    float s[2][4], ss[2][4];
#pragma unroll
    for (int i = 0; i < 2; ++i)
#pragma unroll
        for (int r = 0; r < 4; ++r) { s[i][r] = 0.f; ss[i][r] = 0.f; }
#pragma unroll
    for (int j = 0; j < 4; ++j) {
        int n = w * 64 + j * 16 + lr;
        float bv = bias[n];
#pragma unroll
        for (int i = 0; i < 2; ++i) {
#pragma unroll
            for (int r = 0; r < 4; ++r) {
                int m = m0 + i * 16 + lg * 4 + r;
                float v = acc[i][j][r] + bv + xq[(size_t)m * Cc + n];
                acc[i][j][r] = v;
                xq[(size_t)m * Cc + n] = v;
                s[i][r] += v;
                ss[i][r] += v * v;
            }
        }
    }
#pragma unroll
    for (int i = 0; i < 2; ++i)
#pragma unroll
        for (int r = 0; r < 4; ++r) {
#pragma unroll
            for (int off = 1; off < 16; off <<= 1) {
                s[i][r]  += __shfl_xor(s[i][r], off);
                ss[i][r] += __shfl_xor(ss[i][r], off);
            }
        }
    __syncthreads();
    if (lr == 0) {
#pragma unroll
        for (int i = 0; i < 2; ++i)
#pragma unroll
            for (int r = 0; r < 4; ++r) {
                int row = i * 16 + lg * 4 + r;
                R[row][w][0] = s[i][r];
                R[row][w][1] = ss[i][r];
            }
    }
    __syncthreads();
    if (t < 32) {
        float tot  = R[t][0][0] + R[t][1][0] + R[t][2][0] + R[t][3][0];
        float tots = R[t][0][1] + R[t][1][1] + R[t][2][1] + R[t][3][1];
        float mean = tot * (1.0f / 256.0f);
        float var  = tots * (1.0f / 256.0f) - mean * mean;
        MI[t][0] = mean;
        MI[t][1] = rsqrtf(var + 1e-6f);
    }
    __syncthreads();
#pragma unroll
    for (int j = 0; j < 4; ++j) {
        int n = w * 64 + j * 16 + lr;
        float gv = g[n], bbv = bb[n];
#pragma unroll
        for (int i = 0; i < 2; ++i) {
#pragma unroll
            for (int r = 0; r < 4; ++r) {
                int row = i * 16 + lg * 4 + r;
                float mean = MI[row][0], inv = MI[row][1];
                int m = m0 + row;
                ybf[(size_t)m * Cc + n] = f2bf((acc[i][j][r] - mean) * inv * gv + bbv);
            }
        }
    }
}

// ---------------- fused QKV GEMM, 64x128 tile (870 blocks), N=768, K=256 ----------------
__global__ __launch_bounds__(256) void mfma_gemm_qkv64_kernel(
    const u16* __restrict__ A, const u16* __restrict__ W,
    const float* __restrict__ q_b, const float* __restrict__ k_b, const float* __restrict__ v_b,
    u16* __restrict__ outq, u16* __restrict__ outk, u16* __restrict__ outkt, u16* __restrict__ outv)
{
    const int M = MRc, K = Cc;
    __shared__ u16 As[64 * 64];
    __shared__ u16 Bs[128 * 64];
    int t = threadIdx.x;
    int w = t >> 6, l = t & 63, lg = l >> 4, lr = l & 15;
    int wm = w >> 1, wn = w & 1;
    int m0 = blockIdx.y * 64, n0 = blockIdx.x * 128;
    int range = n0 >> 8;  // n0 in {0,128,256,384,512,640} -> 0,0,1,1,2,2
    f32x4 acc[2][4] = {};
    int lrow = l >> 3, lchunk = (l & 7) * 8;
    for (int k0 = 0; k0 < K; k0 += 64) {
        __syncthreads();
#pragma unroll
        for (int c = 0; c < 2; ++c) {
            int ar = m0 + w * 16 + c * 8 + lrow;
            if (ar >= M) ar = M - 1;
            gload16(A + (size_t)ar * K + k0 + lchunk, As + (w * 16 + c * 8) * 64);
        }
#pragma unroll
        for (int c = 0; c < 4; ++c) {
            int br = n0 + w * 32 + c * 8 + lrow;
            gload16(W + (size_t)br * K + k0 + lchunk, Bs + (w * 32 + c * 8) * 64);
        }
        __syncthreads();
#pragma unroll
        for (int kk = 0; kk < 64; kk += 32) {
            s8v aF[2], bF[4];
#pragma unroll
            for (int i = 0; i < 2; ++i)
                aF[i] = *(s8v*)&As[(wm * 32 + i * 16 + lr) * 64 + kk + lg * 8];
#pragma unroll
            for (int j = 0; j < 4; ++j)
                bF[j] = *(s8v*)&Bs[(wn * 64 + j * 16 + lr) * 64 + kk + lg * 8];
#pragma unroll
            for (int i = 0; i < 2; ++i)
#pragma unroll
                for (int j = 0; j < 4; ++j)
                    acc[i][j] = __builtin_amdgcn_mfma_f32_16x16x32_bf16(aF[i], bF[j], acc[i][j], 0, 0, 0);
        }
    }
    const float* bias = (range == 0) ? q_b : (range == 1) ? k_b : v_b;
    u16* dst = (range == 0) ? outq : (range == 1) ? outk : outv;
    float scale = (range == 0) ? LOG2Ec : (range == 1) ? KSCALEc : 1.0f;
#pragma unroll
    for (int j = 0; j < 4; ++j) {
        int n = n0 + wn * 64 + j * 16 + lr;
        int nc = n & 255;
        float bv = bias[nc];
#pragma unroll
        for (int i = 0; i < 2; ++i) {
#pragma unroll
            for (int r = 0; r < 4; ++r) {
                int m = m0 + wm * 32 + i * 16 + lg * 4 + r;
                if (m >= M) continue;
                float v = (acc[i][j][r] + bv) * scale;
                u16 hv = f2bf(v);
                dst[(size_t)m * 256 + nc] = hv;
                if (range == 1) {
                    unsigned um = (unsigned)m;
                    unsigned bb = um / 2312u;
                    unsigned nr = um - bb * 2312u;
                    outkt[((size_t)(bb * NHc + (nc >> 5)) * Dc + (nc & 31)) * KTLDc + nr] = hv;
                }
            }
        }
    }
}

// ---------------- MFMA flash attention + co-launched lepe conv (blocks >= 1184) ----------------
__global__ __launch_bounds__(256, 4) void attn_mfma_kernel(const u16* __restrict__ q,
                                                           const u16* __restrict__ k,
                                                           const u16* __restrict__ kt,
                                                           const u16* __restrict__ p,
                                                           u16* __restrict__ o,
                                                           const u16* __restrict__ v,
                                                           const float* __restrict__ lw,
                                                           const float* __restrict__ lbias,
                                                           u16* __restrict__ lepebf)
{
    constexpr int KT = 64;
    constexpr int NT = (Nc + KT - 1) / KT;  // 37
    __shared__ __align__(16) u16 Kls[KT * 40];     // [kv][d]
    __shared__ __align__(16) u16 Ktls[32 * 88];    // [d][kv]
    __shared__ __align__(16) unsigned PW[4][16 * 36]; // per-wave packed P

    int flat = blockIdx.x;
    if (flat >= 1184) {
        // ---- lepe path: fills idle occupancy while attn blocks run ----
        int idx = (flat - 1184) * 256 + threadIdx.x;   // 294912 units
        int cg = (idx & 31) * 8;
        int sp = idx >> 5;
        int ww = sp % Wc;
        int t2 = sp / Wc;
        int hh = t2 % Hc;
        int b  = t2 / Hc;
        float acc[8];
#pragma unroll
        for (int i = 0; i < 8; ++i) acc[i] = lbias[cg + i];
#pragma unroll
        for (int kh = 0; kh < 5; ++kh) {
            int yy = hh + kh - 2;
            if (yy < 0 || yy >= Hc) continue;
#pragma unroll
            for (int kw = 0; kw < 5; ++kw) {
                int xx = ww + kw - 2;
                if (xx < 0 || xx >= Wc) continue;
                union { s8v s; u16 u[8]; } uv;
                uv.s = *(const s8v*)&v[((size_t)b * Nc + NQc + yy * Wc + xx) * Cc + cg];
                const float4* wp = (const float4*)&lw[(kh * 5 + kw) * Cc + cg];
                float4 w0 = wp[0], w1 = wp[1];
                acc[0] += bf2f(uv.u[0]) * w0.x;
                acc[1] += bf2f(uv.u[1]) * w0.y;
                acc[2] += bf2f(uv.u[2]) * w0.z;
                acc[3] += bf2f(uv.u[3]) * w0.w;
                acc[4] += bf2f(uv.u[4]) * w1.x;
                acc[5] += bf2f(uv.u[5]) * w1.y;
                acc[6] += bf2f(uv.u[6]) * w1.z;
                acc[7] += bf2f(uv.u[7]) * w1.w;
            }
        }
        union { s8v s; u16 u[8]; } res;
#pragma unroll
        for (int i = 0; i < 8; ++i) res.u[i] = f2bf(acc[i]);
        *(s8v*)&lepebf[((size_t)t2 * Wc + ww) * Cc + cg] = res.s;
        return;
    }

    int grp  = flat & 31;       // (b,h) group -> XCD-local
    int qblk = flat >> 5;       // 0..36
    int b = grp >> 3, h = grp & 7;

    int t = threadIdx.x;
    int w = t >> 6, l = t & 63, lg = l >> 4, lr = l & 15;
    int q0 = qblk * 64 + w * 16;

    int qrow = q0 + lr;
    bool qtok = (qrow < NQc);
    int qrc = qrow < Nc ? qrow : Nc - 1;
    s8v qB = *(const s8v*)&q[((size_t)b * Nc + qrc) * Cc + h * Dc + lg * 8];

    s8v pqB = {0, 0, 0, 0, 0, 0, 0, 0};
    if (lg == 0 && qrow >= NQc && qrow < Nc)
        pqB = *(const s8v*)&p[((size_t)b * HWc + (qrow - NQc)) * 8];

    f32x4 accO[2] = {{0.f, 0.f, 0.f, 0.f}, {0.f, 0.f, 0.f, 0.f}};
    float lrun = 0.f;

    int srow = t >> 2, sseg = (t & 3) * 8;     // K staging
    int td = t >> 3, tks = (t & 7) * 8;        // Kt staging
    const u16* ktbase = kt + ((size_t)(b * NHc + h) * Dc + td) * KTLDc;
    const u16* pbase  = p + (size_t)b * HWc * 8;
    unsigned* PWr = &PW[w][lr * 36];
    int bsrc = lg * 20;  // broadcast source lane base

    s8v kv8 = {0,0,0,0,0,0,0,0};
    if (srow < Nc)
        kv8 = *(const s8v*)&k[((size_t)b * Nc + srow) * Cc + h * Dc + sseg];
    s8v kt8 = *(const s8v*)&ktbase[tks];

    for (int ti = 0; ti < NT; ++ti) {
        int m0 = ti * KT;
        bool tail = (ti == NT - 1);
        __syncthreads();
        *(s8v*)&Kls[srow * 40 + sseg] = kv8;
        *(s8v*)&Ktls[td * 88 + tks]   = kt8;
        __syncthreads();

        if (ti + 1 < NT) {
            int n0g = m0 + KT;
            kv8 = (s8v){0,0,0,0,0,0,0,0};
            int kvg = n0g + srow;
            if (kvg < Nc)
                kv8 = *(const s8v*)&k[((size_t)b * Nc + kvg) * Cc + h * Dc + sseg];
            kt8 = *(const s8v*)&ktbase[n0g + tks];
        }

        float sc[4][4];
#pragma unroll
        for (int cb = 0; cb < 4; ++cb) {
            s8v kA = *(s8v*)&Kls[(cb * 16 + lr) * 40 + lg * 8];
            f32x4 St = __builtin_amdgcn_mfma_f32_16x16x32_bf16(kA, qB, (f32x4){0.f,0.f,0.f,0.f}, 0, 0, 0);
            s8v pkA = {0, 0, 0, 0, 0, 0, 0, 0};
            if (lg == 0) {
                int kvr = m0 + cb * 16 + lr;
                if (kvr >= NQc && kvr < Nc)
                    pkA = *(const s8v*)&pbase[(size_t)(kvr - NQc) * 8];
            }
            f32x4 Mv = __builtin_amdgcn_mfma_f32_16x16x32_bf16(pkA, pqB, (f32x4){0.f,0.f,0.f,0.f}, 0, 0, 0);
            bool ktok = (ti == 0 && cb == 0 && lg < 2);  // kv-row < 8
#pragma unroll
            for (int j = 0; j < 4; ++j) {
                float mval = (qtok || ktok) ? 1.f : Mv[j];
                sc[cb][j] = St[j] * mval;
            }
        }
        // softmax numerator: q pre-scaled by log2e -> raw v_exp_f32 (fixed shift 0, |S|<=~2)
        float tsum = 0.f;
#pragma unroll
        for (int cb = 0; cb < 4; ++cb)
#pragma unroll
            for (int j = 0; j < 4; ++j) {
                float ev = fast_exp2(sc[cb][j]);
                if (tail && (cb != 0 || lg >= 2)) ev = 0.f;  // kv >= Nc
                sc[cb][j] = ev;
                tsum += ev;
            }
        tsum += __shfl_xor(tsum, 16);
        tsum += __shfl_xor(tsum, 32);
        lrun += tsum;
#pragma unroll
        for (int cb = 0; cb < 4; ++cb) {
            uint2 pk2;
            pk2.x = cvtpk2(sc[cb][0], sc[cb][1]);
            pk2.y = cvtpk2(sc[cb][2], sc[cb][3]);
            *(uint2*)&PWr[8 * cb + 2 * lg] = pk2;
        }
#pragma unroll
        for (int kc = 0; kc < 2; ++kc) {
            s8v pA = *(s8v*)&PWr[16 * kc + 4 * lg];
#pragma unroll
            for (int db = 0; db < 2; ++db) {
                s8v vB = *(s8v*)&Ktls[(db * 16 + lr) * 88 + kc * 32 + lg * 8];
                accO[db] = __builtin_amdgcn_mfma_f32_16x16x32_bf16(pA, vB, accO[db], 0, 0, 0);
            }
        }
    }

    float lb[4];
#pragma unroll
    for (int j = 0; j < 4; ++j) lb[j] = __shfl(lrun, bsrc + j);
#pragma unroll
    for (int db = 0; db < 2; ++db)
#pragma unroll
        for (int j = 0; j < 4; ++j) {
            int rowg = q0 + lg * 4 + j;
            if (rowg < Nc)
                o[((size_t)b * Nc + rowg) * Cc + h * Dc + db * 16 + lr] = f2bf(accO[db][j] / lb[j]);
        }
}

extern "C" void kernel_launch(void* const* d_in, const int* in_sizes, int n_in,
                              void* d_out, int out_size, void* d_ws, size_t ws_size,
                              hipStream_t stream)
{
    const float* x       = (const float*)d_in[0];
    const float* queries = (const float*)d_in[1];
    const int*   epoch   = (const int*)d_in[2];
    const float* pos_w   = (const float*)d_in[3];
    const float* pos_b   = (const float*)d_in[4];
    const float* ln1_g   = (const float*)d_in[5];
    const float* ln1_b   = (const float*)d_in[6];
    const float* q_w     = (const float*)d_in[7];
    const float* q_b     = (const float*)d_in[8];
    const float* k_w     = (const float*)d_in[9];
    const float* k_b     = (const float*)d_in[10];
    const float* v_w     = (const float*)d_in[11];
    const float* v_b     = (const float*)d_in[12];
    const float* lepe_w  = (const float*)d_in[13];
    const float* lepe_b  = (const float*)d_in[14];
    const float* out_w   = (const float*)d_in[15];
    const float* out_b   = (const float*)d_in[16];
    const float* ln2_g   = (const float*)d_in[17];
    const float* ln2_b   = (const float*)d_in[18];
    const float* fc1_w   = (const float*)d_in[19];
    const float* fc1_b   = (const float*)d_in[20];
    const float* fc2_w   = (const float*)d_in[21];
    const float* fc2_b   = (const float*)d_in[22];

    float* ws = (float*)d_ws;
    float* xq  = ws;                        // f32, 2,367,488
    u16*  ybf  = (u16*)(ws + 2367488);      // bf16 2,367,488 (1,183,744 slots)
    u16*  qbf  = (u16*)(ws + 3551232);      // bf16 2,367,488
    u16*  kbf  = (u16*)(ws + 4734976);      // bf16 2,367,488
    u16*  ktbf = (u16*)(ws + 5918720);      // bf16 4*8*32*2368 = 2,424,832 (1,212,416 slots)
    u16*  pbf  = (u16*)(ws + 7131136);      // bf16 73,728 (36,864 slots)
    u16*  obf  = (u16*)(ws + 7168000);      // bf16 2,367,488
    u16*  vbf  = (u16*)(ws + 8351744);      // bf16 2,367,488
    u16*  wbf  = (u16*)(ws + 9535488);      // bf16 786,432 (weights; 393,216 slots)
    u16*  lepebf = (u16*)(ws + 9928704);    // bf16 2,359,296 (lepe conv result)
    u16*  ffn  = qbf;                       // fc1 act aliases qbf..obf (dead by then)

    u16* w_o  = wbf + 196608;
    u16* w_f1 = wbf + 262144;
    u16* w_f2 = wbf + 524288;

    fused_pre_kernel<<<9248 + 768 + 224, 256, 0, stream>>>(
        x, queries, epoch, pos_w, pos_b, ln1_g, ln1_b,
        q_w, k_w, v_w, out_w, fc1_w, fc2_w,
        xq, ybf, pbf, wbf, ktbf);

    mfma_gemm_qkv64_kernel<<<dim3(6, 145), 256, 0, stream>>>(ybf, wbf, q_b, k_b, v_b, qbf, kbf, ktbf, vbf);

    // attn (1184 blocks) + co-launched lepe conv (1152 blocks) fill idle occupancy
    attn_mfma_kernel<<<1184 + 1152, 256, 0, stream>>>(qbf, kbf, ktbf, pbf, obf,
                                                      vbf, lepe_w, lepe_b, lepebf);

    mfma_gemm_oln_kernel<<<289, 256, 0, stream>>>(obf, lepebf, w_o, out_b, xq, ln2_g, ln2_b, ybf);

    mfma_gemm64_kernel<1,0,1><<<dim3(8, 145), 256, 0, stream>>>(ybf, w_f1, fc1_b, nullptr, nullptr, ffn, MRc, 1024, 256, 1.0f);
    mfma_gemm32_kernel<1,3><<<dim3(2, 289), 256, 0, stream>>>(ffn, w_f2, fc2_b, xq, (float*)d_out, MRc, 256, 1024, 1.0f);
}

// Round 24
// 188.986 us; speedup vs baseline: 1.1908x; 1.0064x over previous
//
#include <hip/hip_runtime.h>
#include <hip/hip_bf16.h>
#include <math.h>

typedef unsigned short u16;
constexpr int Bc = 4, Hc = 48, Wc = 48, Cc = 256;
constexpr int NQc = 8, HWc = 2304, Nc = 2312, NHc = 8, Dc = 32, FFNc = 1024;
constexpr int MRc = Bc * Nc; // 9248
constexpr int KTLDc = 2368;  // padded kv length for transposed K (37*64)
constexpr float KSCALEc = 0.17677669529663687f; // (256/8)^-0.5
constexpr float LOG2Ec  = 1.4426950408889634f;

typedef __attribute__((ext_vector_type(8))) short s8v;
typedef __attribute__((ext_vector_type(4))) float f32x4;

__device__ __forceinline__ u16 f2bf(float f) {
    union { __hip_bfloat16 h; u16 u; } c;
    c.h = __float2bfloat16(f);
    return c.u;
}
__device__ __forceinline__ float bf2f(u16 u) {
    return __uint_as_float(((unsigned)u) << 16);
}
__device__ __forceinline__ unsigned cvtpk2(float lo, float hi) {
    unsigned r;
    asm("v_cvt_pk_bf16_f32 %0, %1, %2" : "=v"(r) : "v"(lo), "v"(hi));
    return r;
}
// raw v_exp_f32 (2^x), no OCML range fixup
__device__ __forceinline__ float fast_exp2(float x) {
    float r;
    asm("v_exp_f32 %0, %1" : "=v"(r) : "v"(x));
    return r;
}
// async global->LDS, 16B per lane; lds dest is wave-uniform base + lane*16
__device__ __forceinline__ void gload16(const void* g, void* l) {
    __builtin_amdgcn_global_load_lds((const __attribute__((address_space(1))) void*)g,
                                     (__attribute__((address_space(3))) void*)l, 16, 0, 0);
}

// ---------------- fused: pre (pos conv + LN1 + region softmax) / weight convert / kt pad-zero ----------------
__global__ __launch_bounds__(256) void fused_pre_kernel(
    const float* __restrict__ x, const float* __restrict__ queries, const int* __restrict__ epoch,
    const float* __restrict__ pos_w, const float* __restrict__ pos_b,
    const float* __restrict__ ln_g, const float* __restrict__ ln_b,
    const float* __restrict__ qw, const float* __restrict__ kw, const float* __restrict__ vw,
    const float* __restrict__ ow, const float* __restrict__ f1, const float* __restrict__ f2,
    float* __restrict__ xq, u16* __restrict__ ybf, u16* __restrict__ pbf,
    u16* __restrict__ wbf, u16* __restrict__ kt)
{
    int bi = blockIdx.x;
    if (bi >= 9248) {
        int bj = bi - 9248;
        if (bj < 768) {
            int i4 = bj * 256 + threadIdx.x;
            int idx = i4 * 4;
            const float* src; int off;
            if      (idx < 65536)  { src = qw; off = idx; }
            else if (idx < 131072) { src = kw; off = idx - 65536; }
            else if (idx < 196608) { src = vw; off = idx - 131072; }
            else if (idx < 262144) { src = ow; off = idx - 196608; }
            else if (idx < 524288) { src = f1; off = idx - 262144; }
            else                   { src = f2; off = idx - 524288; }
            float4 v = *(const float4*)(src + off);
            ushort4 o;
            o.x = f2bf(v.x); o.y = f2bf(v.y); o.z = f2bf(v.z); o.w = f2bf(v.w);
            *(ushort4*)(wbf + idx) = o;
        } else {
            int idx = (bj - 768) * 256 + threadIdx.x;  // 1024 rows * 56 pad cols
            if (idx < 1024 * 56) {
                int row = idx / 56, col = idx - row * 56;
                kt[(size_t)row * KTLDc + 2312 + col] = 0;
            }
        }
        return;
    }
    int blk = bi;                        // 0..9247
    int b = blk / Nc, n = blk - b * Nc;
    int c = threadIdx.x;
    bool sp = (n >= NQc);
    float val;
    if (sp) {
        int s = n - NQc;
        int hh = s / Wc, ww = s - hh * Wc;
        float acc = pos_b[c];
        float center = x[((b * Hc + hh) * Wc + ww) * Cc + c];
#pragma unroll
        for (int kh = 0; kh < 3; ++kh) {
            int yy = hh + kh - 1;
            if (yy < 0 || yy >= Hc) continue;
#pragma unroll
            for (int kw2 = 0; kw2 < 3; ++kw2) {
                int xx = ww + kw2 - 1;
                if (xx < 0 || xx >= Wc) continue;
                acc += x[((b * Hc + yy) * Wc + xx) * Cc + c] * pos_w[(kh * 3 + kw2) * Cc + c];
            }
        }
        val = center + acc;
    } else {
        val = queries[(b * NQc + n) * Cc + c];
    }
    xq[(size_t)blk * Cc + c] = val;

    float pq[8];
#pragma unroll
    for (int qi = 0; qi < 8; ++qi)
        pq[qi] = sp ? val * queries[(b * NQc + qi) * Cc + c] : 0.f;
    float r0 = val, r1 = val * val;
#pragma unroll
    for (int off = 32; off; off >>= 1) {
        r0 += __shfl_xor(r0, off);
        r1 += __shfl_xor(r1, off);
#pragma unroll
        for (int qi = 0; qi < 8; ++qi) pq[qi] += __shfl_xor(pq[qi], off);
    }
    __shared__ float red[4][10];
    __shared__ float fin[10];
    int wv = c >> 6, ln = c & 63;
    if (ln == 0) {
        red[wv][0] = r0; red[wv][1] = r1;
#pragma unroll
        for (int qi = 0; qi < 8; ++qi) red[wv][2 + qi] = pq[qi];
    }
    __syncthreads();
    if (c < 10) fin[c] = red[0][c] + red[1][c] + red[2][c] + red[3][c];
    __syncthreads();
    float mean = fin[0] * (1.0f / 256.0f);
    float var  = fin[1] * (1.0f / 256.0f) - mean * mean;
    float inv  = rsqrtf(var + 1e-6f);
    ybf[(size_t)blk * Cc + c] = f2bf((val - mean) * inv * ln_g[c] + ln_b[c]);

    if (sp && c < 8) {
        float it = 1.0f / (2.0f * powf(0.05f, (float)(*epoch) / 200.0f));
        float mx = -1e30f;
        float lg[8];
#pragma unroll
        for (int qi = 0; qi < 8; ++qi) { lg[qi] = fin[2 + qi] * it; mx = fmaxf(mx, lg[qi]); }
        float s = 0.f, mine = 0.f;
#pragma unroll
        for (int qi = 0; qi < 8; ++qi) {
            float ev = __expf(lg[qi] - mx);
            s += ev;
            if (qi == c) mine = ev;
        }
        pbf[((size_t)b * HWc + (n - NQc)) * 8 + c] = f2bf(mine / s);
    }
}

// ---------------- 64x128-tile GEMM (high block-count variant) ----------------
// OMODE: 0=f32 out, 1=bf16 out, 3=f32 out permuted to d_out layout (N==256)
template <int ACT, int RESID, int OMODE>
__global__ __launch_bounds__(256) void mfma_gemm64_kernel(
    const u16* __restrict__ A, const u16* __restrict__ W,
    const float* __restrict__ bias, const float* resid,
    float* outF, u16* outB, int M, int N, int K, float scale)
{
    __shared__ u16 As[64 * 64];
    __shared__ u16 Bs[128 * 64];
    int t = threadIdx.x;
    int w = t >> 6, l = t & 63, lg = l >> 4, lr = l & 15;
    int wm = w >> 1, wn = w & 1;
    int m0 = blockIdx.y * 64, n0 = blockIdx.x * 128;
    f32x4 acc[2][4] = {};
    int lrow = l >> 3, lchunk = (l & 7) * 8;
    for (int k0 = 0; k0 < K; k0 += 64) {
        __syncthreads();
#pragma unroll
        for (int c = 0; c < 2; ++c) {
            int ar = m0 + w * 16 + c * 8 + lrow;
            if (ar >= M) ar = M - 1;
            gload16(A + (size_t)ar * K + k0 + lchunk, As + (w * 16 + c * 8) * 64);
        }
#pragma unroll
        for (int c = 0; c < 4; ++c) {
            int br = n0 + w * 32 + c * 8 + lrow;
            gload16(W + (size_t)br * K + k0 + lchunk, Bs + (w * 32 + c * 8) * 64);
        }
        __syncthreads();
#pragma unroll
        for (int kk = 0; kk < 64; kk += 32) {
            s8v aF[2], bF[4];
#pragma unroll
            for (int i = 0; i < 2; ++i)
                aF[i] = *(s8v*)&As[(wm * 32 + i * 16 + lr) * 64 + kk + lg * 8];
#pragma unroll
            for (int j = 0; j < 4; ++j)
                bF[j] = *(s8v*)&Bs[(wn * 64 + j * 16 + lr) * 64 + kk + lg * 8];
#pragma unroll
            for (int i = 0; i < 2; ++i)
#pragma unroll
                for (int j = 0; j < 4; ++j)
                    acc[i][j] = __builtin_amdgcn_mfma_f32_16x16x32_bf16(aF[i], bF[j], acc[i][j], 0, 0, 0);
        }
    }
#pragma unroll
    for (int j = 0; j < 4; ++j) {
        int n = n0 + wn * 64 + j * 16 + lr;
        float bv = bias[n];
#pragma unroll
        for (int i = 0; i < 2; ++i) {
#pragma unroll
            for (int r = 0; r < 4; ++r) {
                int m = m0 + wm * 32 + i * 16 + lg * 4 + r;
                if (m >= M) continue;
                float v = (acc[i][j][r] + bv) * scale;
                if (ACT == 1) {
                    float e = fast_exp2(2.302118f * (v + 0.044715f * v * v * v));
                    v = v * e * __builtin_amdgcn_rcpf(e + 1.0f);
                }
                if (RESID) v += resid[(size_t)m * N + n];
                if (OMODE == 0) {
                    outF[(size_t)m * N + n] = v;
                } else if (OMODE == 3) {
                    unsigned bb2 = (unsigned)m / 2312u;
                    unsigned tok = (unsigned)m - bb2 * 2312u;
                    size_t ob = (tok >= 8) ? (((size_t)(bb2 * 2304 + tok - 8)) << 8)
                                           : ((size_t)2359296 + (((size_t)(bb2 * 8 + tok)) << 8));
                    outF[ob + n] = v;
                } else {
                    outB[(size_t)m * N + n] = f2bf(v);
                }
            }
        }
    }
}

// ---------------- 32x128-tile GEMM (max block-count, for long-K small-N shapes like fc2) ----------------
template <int RESID, int OMODE>
__global__ __launch_bounds__(256) void mfma_gemm32_kernel(
    const u16* __restrict__ A, const u16* __restrict__ W,
    const float* __restrict__ bias, const float* resid,
    float* outF, int M, int N, int K, float scale)
{
    __shared__ u16 As[32 * 64];    // 4 KB
    __shared__ u16 Bs[128 * 64];   // 16 KB
    int t = threadIdx.x;
    int w = t >> 6, l = t & 63, lg = l >> 4, lr = l & 15;
    int wm = w >> 1, wn = w & 1;   // wave = 16 rows x 64 cols
    int m0 = blockIdx.y * 32, n0 = blockIdx.x * 128;
    f32x4 acc[4] = {};
    int lrow = l >> 3, lchunk = (l & 7) * 8;
    for (int k0 = 0; k0 < K; k0 += 64) {
        __syncthreads();
        {   // A: 32 rows, wave w stages rows w*8..w*8+7
            int ar = m0 + w * 8 + lrow;
            if (ar >= M) ar = M - 1;
            gload16(A + (size_t)ar * K + k0 + lchunk, As + (w * 8) * 64);
        }
#pragma unroll
        for (int c = 0; c < 4; ++c) {
            int br = n0 + w * 32 + c * 8 + lrow;
            gload16(W + (size_t)br * K + k0 + lchunk, Bs + (w * 32 + c * 8) * 64);
        }
        __syncthreads();
#pragma unroll
        for (int kk = 0; kk < 64; kk += 32) {
            s8v aF = *(s8v*)&As[(wm * 16 + lr) * 64 + kk + lg * 8];
#pragma unroll
            for (int j = 0; j < 4; ++j) {
                s8v bF = *(s8v*)&Bs[(wn * 64 + j * 16 + lr) * 64 + kk + lg * 8];
                acc[j] = __builtin_amdgcn_mfma_f32_16x16x32_bf16(aF, bF, acc[j], 0, 0, 0);
            }
        }
    }
#pragma unroll
    for (int j = 0; j < 4; ++j) {
        int n = n0 + wn * 64 + j * 16 + lr;
        float bv = bias[n];
#pragma unroll
        for (int r = 0; r < 4; ++r) {
            int m = m0 + wm * 16 + lg * 4 + r;
            if (m >= M) continue;
            float v = (acc[j][r] + bv) * scale;
            if (RESID) v += resid[(size_t)m * N + n];
            if (OMODE == 0) {
                outF[(size_t)m * N + n] = v;
            } else {
                unsigned bb2 = (unsigned)m / 2312u;
                unsigned tok = (unsigned)m - bb2 * 2312u;
                size_t ob = (tok >= 8) ? (((size_t)(bb2 * 2304 + tok - 8)) << 8)
                                       : ((size_t)2359296 + (((size_t)(bb2 * 8 + tok)) << 8));
                outF[ob + n] = v;
            }
        }
    }
}

// ---------------- fused out-proj(+lepe A-sum) + residual + LN2: 16x256 tile, 578 blocks ----------------
__global__ __launch_bounds__(256) void mfma_gemm_oln_kernel(
    const u16* __restrict__ A, const u16* __restrict__ L,
    const u16* __restrict__ W, const float* __restrict__ bias,
    float* __restrict__ xq, const float* __restrict__ g, const float* __restrict__ bb,
    u16* __restrict__ ybf)
{
    const int K = Cc;
    constexpr int ALD = 264;        // padded A row stride (u16): 528 B -> 2-way banks on stride-16 reads
    __shared__ u16 As[16 * ALD];    // 8.25 KB, full-K A tile staged once
    __shared__ u16 Bs[256 * 64];    // 32 KB
    __shared__ float R[16][4][2];
    __shared__ float MI[16][2];
    int t = threadIdx.x;
    int w = t >> 6, l = t & 63, lg = l >> 4, lr = l & 15;
    int m0 = blockIdx.x * 16;
    int lrow = l >> 3, lchunk = (l & 7) * 8;

    // stage A = obf + lepe (coalesced pair-load + add, 2 units/thread)
    for (int u = t; u < 512; u += 256) {
        int row = u >> 5;
        int cg  = (u & 31) * 8;
        int m = m0 + row;
        int b2 = m / 2312, n = m - b2 * 2312;
        union { s8v s; u16 us[8]; } ov, res;
        ov.s = *(const s8v*)&A[(size_t)m * Cc + cg];
        if (n >= NQc) {
            union { s8v s; u16 us[8]; } lv;
            lv.s = *(const s8v*)&L[((size_t)b2 * HWc + (n - NQc)) * Cc + cg];
#pragma unroll
            for (int i = 0; i < 8; ++i) res.us[i] = f2bf(bf2f(ov.us[i]) + bf2f(lv.us[i]));
        } else {
            res.s = ov.s;
        }
        *(s8v*)&As[row * ALD + cg] = res.s;
    }

    f32x4 acc[4] = {};
    for (int k0 = 0; k0 < K; k0 += 64) {
        __syncthreads();   // first iteration also covers As ds_writes
#pragma unroll
        for (int c = 0; c < 8; ++c)
            gload16(W + (size_t)(w * 64 + c * 8 + lrow) * K + k0 + lchunk, Bs + (w * 64 + c * 8) * 64);
        __syncthreads();
#pragma unroll
        for (int kk = 0; kk < 64; kk += 32) {
            s8v aF = *(s8v*)&As[lr * ALD + k0 + kk + lg * 8];
#pragma unroll
            for (int j = 0; j < 4; ++j) {
                s8v bF = *(s8v*)&Bs[(w * 64 + j * 16 + lr) * 64 + kk + lg * 8];
                acc[j] = __builtin_amdgcn_mfma_f32_16x16x32_bf16(aF, bF, acc[j], 0, 0, 0);
            }
        }
    }
    float s[4], ss[4];
#pragma unroll
    for (int r = 0; r < 4; ++r) { s[r] = 0.f; ss[r] = 0.f; }
#pragma unroll
    for (int j = 0; j < 4; ++j) {
        int n = w * 64 + j * 16 + lr;
        float bv = bias[n];
#pragma unroll
        for (int r = 0; r < 4; ++r) {
            int m = m0 + lg * 4 + r;
            float v = acc[j][r] + bv + xq[(size_t)m * Cc + n];
            acc[j][r] = v;
            xq[(size_t)m * Cc + n] = v;
            s[r] += v;
            ss[r] += v * v;
        }
    }
#pragma unroll
    for (int r = 0; r < 4; ++r) {
#pragma unroll
        for (int off = 1; off < 16; off <<= 1) {
            s[r]  += __shfl_xor(s[r], off);
            ss[r] += __shfl_xor(ss[r], off);
        }
    }
    __syncthreads();
    if (lr == 0) {
#pragma unroll
        for (int r = 0; r < 4; ++r) {
            int row = lg * 4 + r;
            R[row][w][0] = s[r];
            R[row][w][1] = ss[r];
        }
    }
    __syncthreads();
    if (t < 16) {
        float tot  = R[t][0][0] + R[t][1][0] + R[t][2][0] + R[t][3][0];
        float tots = R[t][0][1] + R[t][1][1] + R[t][2][1] + R[t][3][1];
        float mean = tot * (1.0f / 256.0f);
        float var  = tots * (1.0f / 256.0f) - mean * mean;
        MI[t][0] = mean;
        MI[t][1] = rsqrtf(var + 1e-6f);
    }
    __syncthreads();
#pragma unroll
    for (int j = 0; j < 4; ++j) {
        int n = w * 64 + j * 16 + lr;
        float gv = g[n], bbv = bb[n];
#pragma unroll
        for (int r = 0; r < 4; ++r) {
            int row = lg * 4 + r;
            float mean = MI[row][0], inv = MI[row][1];
            int m = m0 + row;
            ybf[(size_t)m * Cc + n] = f2bf((acc[j][r] - mean) * inv * gv + bbv);
        }
    }
}

// ---------------- fused QKV GEMM, 64x128 tile (870 blocks), N=768, K=256 ----------------
__global__ __launch_bounds__(256) void mfma_gemm_qkv64_kernel(
    const u16* __restrict__ A, const u16* __restrict__ W,
    const float* __restrict__ q_b, const float* __restrict__ k_b, const float* __restrict__ v_b,
    u16* __restrict__ outq, u16* __restrict__ outk, u16* __restrict__ outkt, u16* __restrict__ outv)
{
    const int M = MRc, K = Cc;
    __shared__ u16 As[64 * 64];
    __shared__ u16 Bs[128 * 64];
    int t = threadIdx.x;
    int w = t >> 6, l = t & 63, lg = l >> 4, lr = l & 15;
    int wm = w >> 1, wn = w & 1;
    int m0 = blockIdx.y * 64, n0 = blockIdx.x * 128;
    int range = n0 >> 8;  // n0 in {0,128,256,384,512,640} -> 0,0,1,1,2,2
    f32x4 acc[2][4] = {};
    int lrow = l >> 3, lchunk = (l & 7) * 8;
    for (int k0 = 0; k0 < K; k0 += 64) {
        __syncthreads();
#pragma unroll
        for (int c = 0; c < 2; ++c) {
            int ar = m0 + w * 16 + c * 8 + lrow;
            if (ar >= M) ar = M - 1;
            gload16(A + (size_t)ar * K + k0 + lchunk, As + (w * 16 + c * 8) * 64);
        }
#pragma unroll
        for (int c = 0; c < 4; ++c) {
            int br = n0 + w * 32 + c * 8 + lrow;
            gload16(W + (size_t)br * K + k0 + lchunk, Bs + (w * 32 + c * 8) * 64);
        }
        __syncthreads();
#pragma unroll
        for (int kk = 0; kk < 64; kk += 32) {
            s8v aF[2], bF[4];
#pragma unroll
            for (int i = 0; i < 2; ++i)
                aF[i] = *(s8v*)&As[(wm * 32 + i * 16 + lr) * 64 + kk + lg * 8];
#pragma unroll
            for (int j = 0; j < 4; ++j)
                bF[j] = *(s8v*)&Bs[(wn * 64 + j * 16 + lr) * 64 + kk + lg * 8];
#pragma unroll
            for (int i = 0; i < 2; ++i)
#pragma unroll
                for (int j = 0; j < 4; ++j)
                    acc[i][j] = __builtin_amdgcn_mfma_f32_16x16x32_bf16(aF[i], bF[j], acc[i][j], 0, 0, 0);
        }
    }
    const float* bias = (range == 0) ? q_b : (range == 1) ? k_b : v_b;
    u16* dst = (range == 0) ? outq : (range == 1) ? outk : outv;
    float scale = (range == 0) ? LOG2Ec : (range == 1) ? KSCALEc : 1.0f;
#pragma unroll
    for (int j = 0; j < 4; ++j) {
        int n = n0 + wn * 64 + j * 16 + lr;
        int nc = n & 255;
        float bv = bias[nc];
#pragma unroll
        for (int i = 0; i < 2; ++i) {
#pragma unroll
            for (int r = 0; r < 4; ++r) {
                int m = m0 + wm * 32 + i * 16 + lg * 4 + r;
                if (m >= M) continue;
                float v = (acc[i][j][r] + bv) * scale;
                u16 hv = f2bf(v);
                dst[(size_t)m * 256 + nc] = hv;
                if (range == 1) {
                    unsigned um = (unsigned)m;
                    unsigned bb = um / 2312u;
                    unsigned nr = um - bb * 2312u;
                    outkt[((size_t)(bb * NHc + (nc >> 5)) * Dc + (nc & 31)) * KTLDc + nr] = hv;
                }
            }
        }
    }
}

// ---------------- MFMA flash attention + co-launched lepe conv (blocks >= 1184) ----------------
__global__ __launch_bounds__(256, 4) void attn_mfma_kernel(const u16* __restrict__ q,
                                                           const u16* __restrict__ k,
                                                           const u16* __restrict__ kt,
                                                           const u16* __restrict__ p,
                                                           u16* __restrict__ o,
                                                           const u16* __restrict__ v,
                                                           const float* __restrict__ lw,
                                                           const float* __restrict__ lbias,
                                                           u16* __restrict__ lepebf)
{
    constexpr int KT = 64;
    constexpr int NT = (Nc + KT - 1) / KT;  // 37
    __shared__ __align__(16) u16 Kls[KT * 40];     // [kv][d]
    __shared__ __align__(16) u16 Ktls[32 * 88];    // [d][kv]
    __shared__ __align__(16) unsigned PW[4][16 * 36]; // per-wave packed P

    int flat = blockIdx.x;
    if (flat >= 1184) {
        // ---- lepe path: fills idle occupancy while attn blocks run ----
        int idx = (flat - 1184) * 256 + threadIdx.x;   // 294912 units
        int cg = (idx & 31) * 8;
        int sp = idx >> 5;
        int ww = sp % Wc;
        int t2 = sp / Wc;
        int hh = t2 % Hc;
        int b  = t2 / Hc;
        float acc[8];
#pragma unroll
        for (int i = 0; i < 8; ++i) acc[i] = lbias[cg + i];
#pragma unroll
        for (int kh = 0; kh < 5; ++kh) {
            int yy = hh + kh - 2;
            if (yy < 0 || yy >= Hc) continue;
#pragma unroll
            for (int kw = 0; kw < 5; ++kw) {
                int xx = ww + kw - 2;
                if (xx < 0 || xx >= Wc) continue;
                union { s8v s; u16 u[8]; } uv;
                uv.s = *(const s8v*)&v[((size_t)b * Nc + NQc + yy * Wc + xx) * Cc + cg];
                const float4* wp = (const float4*)&lw[(kh * 5 + kw) * Cc + cg];
                float4 w0 = wp[0], w1 = wp[1];
                acc[0] += bf2f(uv.u[0]) * w0.x;
                acc[1] += bf2f(uv.u[1]) * w0.y;
                acc[2] += bf2f(uv.u[2]) * w0.z;
                acc[3] += bf2f(uv.u[3]) * w0.w;
                acc[4] += bf2f(uv.u[4]) * w1.x;
                acc[5] += bf2f(uv.u[5]) * w1.y;
                acc[6] += bf2f(uv.u[6]) * w1.z;
                acc[7] += bf2f(uv.u[7]) * w1.w;
            }
        }
        union { s8v s; u16 u[8]; } res;
#pragma unroll
        for (int i = 0; i < 8; ++i) res.u[i] = f2bf(acc[i]);
        *(s8v*)&lepebf[((size_t)t2 * Wc + ww) * Cc + cg] = res.s;
        return;
    }

    int grp  = flat & 31;       // (b,h) group -> XCD-local
    int qblk = flat >> 5;       // 0..36
    int b = grp >> 3, h = grp & 7;

    int t = threadIdx.x;
    int w = t >> 6, l = t & 63, lg = l >> 4, lr = l & 15;
    int q0 = qblk * 64 + w * 16;

    int qrow = q0 + lr;
    bool qtok = (qrow < NQc);
    int qrc = qrow < Nc ? qrow : Nc - 1;
    s8v qB = *(const s8v*)&q[((size_t)b * Nc + qrc) * Cc + h * Dc + lg * 8];

    s8v pqB = {0, 0, 0, 0, 0, 0, 0, 0};
    if (lg == 0 && qrow >= NQc && qrow < Nc)
        pqB = *(const s8v*)&p[((size_t)b * HWc + (qrow - NQc)) * 8];

    f32x4 accO[2] = {{0.f, 0.f, 0.f, 0.f}, {0.f, 0.f, 0.f, 0.f}};
    float lrun = 0.f;

    int srow = t >> 2, sseg = (t & 3) * 8;     // K staging
    int td = t >> 3, tks = (t & 7) * 8;        // Kt staging
    const u16* ktbase = kt + ((size_t)(b * NHc + h) * Dc + td) * KTLDc;
    const u16* pbase  = p + (size_t)b * HWc * 8;
    unsigned* PWr = &PW[w][lr * 36];
    int bsrc = lg * 20;  // broadcast source lane base

    s8v kv8 = {0,0,0,0,0,0,0,0};
    if (srow < Nc)
        kv8 = *(const s8v*)&k[((size_t)b * Nc + srow) * Cc + h * Dc + sseg];
    s8v kt8 = *(const s8v*)&ktbase[tks];

    for (int ti = 0; ti < NT; ++ti) {
        int m0 = ti * KT;
        bool tail = (ti == NT - 1);
        __syncthreads();
        *(s8v*)&Kls[srow * 40 + sseg] = kv8;
        *(s8v*)&Ktls[td * 88 + tks]   = kt8;
        __syncthreads();

        if (ti + 1 < NT) {
            int n0g = m0 + KT;
            kv8 = (s8v){0,0,0,0,0,0,0,0};
            int kvg = n0g + srow;
            if (kvg < Nc)
                kv8 = *(const s8v*)&k[((size_t)b * Nc + kvg) * Cc + h * Dc + sseg];
            kt8 = *(const s8v*)&ktbase[n0g + tks];
        }

        float sc[4][4];
#pragma unroll
        for (int cb = 0; cb < 4; ++cb) {
            s8v kA = *(s8v*)&Kls[(cb * 16 + lr) * 40 + lg * 8];
            f32x4 St = __builtin_amdgcn_mfma_f32_16x16x32_bf16(kA, qB, (f32x4){0.f,0.f,0.f,0.f}, 0, 0, 0);
            s8v pkA = {0, 0, 0, 0, 0, 0, 0, 0};
            if (lg == 0) {
                int kvr = m0 + cb * 16 + lr;
                if (kvr >= NQc && kvr < Nc)
                    pkA = *(const s8v*)&pbase[(size_t)(kvr - NQc) * 8];
            }
            f32x4 Mv = __builtin_amdgcn_mfma_f32_16x16x32_bf16(pkA, pqB, (f32x4){0.f,0.f,0.f,0.f}, 0, 0, 0);
            bool ktok = (ti == 0 && cb == 0 && lg < 2);  // kv-row < 8
#pragma unroll
            for (int j = 0; j < 4; ++j) {
                float mval = (qtok || ktok) ? 1.f : Mv[j];
                sc[cb][j] = St[j] * mval;
            }
        }
        // softmax numerator: q pre-scaled by log2e -> raw v_exp_f32 (fixed shift 0, |S|<=~2)
        float tsum = 0.f;
#pragma unroll
        for (int cb = 0; cb < 4; ++cb)
#pragma unroll
            for (int j = 0; j < 4; ++j) {
                float ev = fast_exp2(sc[cb][j]);
                if (tail && (cb != 0 || lg >= 2)) ev = 0.f;  // kv >= Nc
                sc[cb][j] = ev;
                tsum += ev;
            }
        tsum += __shfl_xor(tsum, 16);
        tsum += __shfl_xor(tsum, 32);
        lrun += tsum;
#pragma unroll
        for (int cb = 0; cb < 4; ++cb) {
            uint2 pk2;
            pk2.x = cvtpk2(sc[cb][0], sc[cb][1]);
            pk2.y = cvtpk2(sc[cb][2], sc[cb][3]);
            *(uint2*)&PWr[8 * cb + 2 * lg] = pk2;
        }
#pragma unroll
        for (int kc = 0; kc < 2; ++kc) {
            s8v pA = *(s8v*)&PWr[16 * kc + 4 * lg];
#pragma unroll
            for (int db = 0; db < 2; ++db) {
                s8v vB = *(s8v*)&Ktls[(db * 16 + lr) * 88 + kc * 32 + lg * 8];
                accO[db] = __builtin_amdgcn_mfma_f32_16x16x32_bf16(pA, vB, accO[db], 0, 0, 0);
            }
        }
    }

    float lb[4];
#pragma unroll
    for (int j = 0; j < 4; ++j) lb[j] = __shfl(lrun, bsrc + j);
#pragma unroll
    for (int db = 0; db < 2; ++db)
#pragma unroll
        for (int j = 0; j < 4; ++j) {
            int rowg = q0 + lg * 4 + j;
            if (rowg < Nc)
                o[((size_t)b * Nc + rowg) * Cc + h * Dc + db * 16 + lr] = f2bf(accO[db][j] / lb[j]);
        }
}

extern "C" void kernel_launch(void* const* d_in, const int* in_sizes, int n_in,
                              void* d_out, int out_size, void* d_ws, size_t ws_size,
                              hipStream_t stream)
{
    const float* x       = (const float*)d_in[0];
    const float* queries = (const float*)d_in[1];
    const int*   epoch   = (const int*)d_in[2];
    const float* pos_w   = (const float*)d_in[3];
    const float* pos_b   = (const float*)d_in[4];
    const float* ln1_g   = (const float*)d_in[5];
    const float* ln1_b   = (const float*)d_in[6];
    const float* q_w     = (const float*)d_in[7];
    const float* q_b     = (const float*)d_in[8];
    const float* k_w     = (const float*)d_in[9];
    const float* k_b     = (const float*)d_in[10];
    const float* v_w     = (const float*)d_in[11];
    const float* v_b     = (const float*)d_in[12];
    const float* lepe_w  = (const float*)d_in[13];
    const float* lepe_b  = (const float*)d_in[14];
    const float* out_w   = (const float*)d_in[15];
    const float* out_b   = (const float*)d_in[16];
    const float* ln2_g   = (const float*)d_in[17];
    const float* ln2_b   = (const float*)d_in[18];
    const float* fc1_w   = (const float*)d_in[19];
    const float* fc1_b   = (const float*)d_in[20];
    const float* fc2_w   = (const float*)d_in[21];
    const float* fc2_b   = (const float*)d_in[22];

    float* ws = (float*)d_ws;
    float* xq  = ws;                        // f32, 2,367,488
    u16*  ybf  = (u16*)(ws + 2367488);      // bf16 2,367,488 (1,183,744 slots)
    u16*  qbf  = (u16*)(ws + 3551232);      // bf16 2,367,488
    u16*  kbf  = (u16*)(ws + 4734976);      // bf16 2,367,488
    u16*  ktbf = (u16*)(ws + 5918720);      // bf16 4*8*32*2368 = 2,424,832 (1,212,416 slots)
    u16*  pbf  = (u16*)(ws + 7131136);      // bf16 73,728 (36,864 slots)
    u16*  obf  = (u16*)(ws + 7168000);      // bf16 2,367,488
    u16*  vbf  = (u16*)(ws + 8351744);      // bf16 2,367,488
    u16*  wbf  = (u16*)(ws + 9535488);      // bf16 786,432 (weights; 393,216 slots)
    u16*  lepebf = (u16*)(ws + 9928704);    // bf16 2,359,296 (lepe conv result)
    u16*  ffn  = qbf;                       // fc1 act aliases qbf..obf (dead by then)

    u16* w_o  = wbf + 196608;
    u16* w_f1 = wbf + 262144;
    u16* w_f2 = wbf + 524288;

    fused_pre_kernel<<<9248 + 768 + 224, 256, 0, stream>>>(
        x, queries, epoch, pos_w, pos_b, ln1_g, ln1_b,
        q_w, k_w, v_w, out_w, fc1_w, fc2_w,
        xq, ybf, pbf, wbf, ktbf);

    mfma_gemm_qkv64_kernel<<<dim3(6, 145), 256, 0, stream>>>(ybf, wbf, q_b, k_b, v_b, qbf, kbf, ktbf, vbf);

    // attn (1184 blocks) + co-launched lepe conv (1152 blocks) fill idle occupancy
    attn_mfma_kernel<<<1184 + 1152, 256, 0, stream>>>(qbf, kbf, ktbf, pbf, obf,
                                                      vbf, lepe_w, lepe_b, lepebf);

    mfma_gemm_oln_kernel<<<578, 256, 0, stream>>>(obf, lepebf, w_o, out_b, xq, ln2_g, ln2_b, ybf);

    mfma_gemm64_kernel<1,0,1><<<dim3(8, 145), 256, 0, stream>>>(ybf, w_f1, fc1_b, nullptr, nullptr, ffn, MRc, 1024, 256, 1.0f);
    mfma_gemm32_kernel<1,3><<<dim3(2, 289), 256, 0, stream>>>(ffn, w_f2, fc2_b, xq, (float*)d_out, MRc, 256, 1024, 1.0f);
}